// Round 3
// baseline (421.549 us; speedup 1.0000x reference)
//
#include <hip/hip_runtime.h>
#include <hip/hip_bf16.h>

#define TK 20
#define BN 65536

typedef const float* fpc;
typedef __attribute__((ext_vector_type(8))) short short8;
typedef __attribute__((ext_vector_type(4))) float floatx4;

// f32 -> bf16 bits, round-to-nearest-even
__device__ __forceinline__ short f2b(float f){
  unsigned u = __float_as_uint(f);
  return (short)((u + 0x7fffu + ((u >> 16) & 1u)) >> 16);
}
__device__ __forceinline__ float b2fu(unsigned short u){
  return __uint_as_float(((unsigned)u) << 16);
}

// --- instrumentation: last-finishing block spins a fixed cycle count so every
// kernel's duration rises above the harness poison-fills and appears in top-5
// with full counters. shown_i = true_i + S; S recovered from dur_us delta. ---
__device__ __forceinline__ void lag_spin(unsigned long long cyc){
  unsigned long long t0 = __builtin_readcyclecounter();
  while (__builtin_readcyclecounter() - t0 < cyc) { }
}
#define LAG_TAIL(CTR) do{ \
    if (threadIdx.x == 0){ \
      int _v = atomicAdd((CTR), 1); \
      if (_v == (int)gridDim.x - 1) lag_spin(120000ULL); \
    } }while(0)

// ---------------- K1: fused graph (blocks 0..255, block 0 zeroes bnsum) + xl MFMA (256..1279) ----------------
__global__ void __launch_bounds__(256) k_gx(fpc data, fpc emb, fpc lin_w, fpc att_i, fpc att_j,
        fpc att_em_i, fpc att_em_j,
        int* __restrict__ topk, float* __restrict__ emi, float* __restrict__ emj,
        __hip_bfloat16* __restrict__ xl, float* __restrict__ aip, float* __restrict__ ajp,
        float* __restrict__ bnsum, int* __restrict__ ctr){
  __shared__ float s_cos[256];
  __shared__ float s_wi[64];
  const int t = threadIdx.x, w = t >> 6, lane = t & 63;

  if (blockIdx.x < 256){
    if (blockIdx.x == 0){
      #pragma unroll
      for (int i = 0; i < 8; ++i) bnsum[t + i*256] = 0.f;   // zero shadow BN accumulators
    }
    // ----- graph part: top-20 cosine + emi/emj -----
    const int i = blockIdx.x;
    if (t < 64) s_wi[t] = emb[i*64 + t];
    __syncthreads();
    float dot = 0.f, nj = 0.f, ni = 0.f;
    for (int f = 0; f < 64; ++f){
      float wj = emb[t*64 + f], wi = s_wi[f];
      dot = fmaf(wi, wj, dot); nj = fmaf(wj, wj, nj); ni = fmaf(wi, wi, ni);
    }
    s_cos[t] = dot / (sqrtf(ni) * sqrtf(nj));
    __syncthreads();
    if (t < 64){
      float v0 = s_cos[t], v1 = s_cos[t+64], v2 = s_cos[t+128], v3 = s_cos[t+192];
      int taken = 0;
      for (int r = 0; r < TK; ++r){
        float bv = (taken & 1) ? -3.f : v0; int bi = t;
        float c;
        c = (taken & 2) ? -3.f : v1; if (c > bv){ bv = c; bi = t+64;  }
        c = (taken & 4) ? -3.f : v2; if (c > bv){ bv = c; bi = t+128; }
        c = (taken & 8) ? -3.f : v3; if (c > bv){ bv = c; bi = t+192; }
        for (int m = 1; m < 64; m <<= 1){
          float ov = __shfl_xor(bv, m, 64);
          int   oi = __shfl_xor(bi, m, 64);
          if (ov > bv || (ov == bv && oi < bi)){ bv = ov; bi = oi; }
        }
        if (t == 0) topk[i*TK + r] = bi;
        if ((bi & 63) == t) taken |= 1 << (bi >> 6);
      }
    } else if (t < 128){
      int d = t - 64;
      float wv = s_wi[d];
      float p1 = wv * att_em_i[d];
      float p2 = wv * att_em_j[d];
      for (int m = 1; m < 64; m <<= 1){
        p1 += __shfl_xor(p1, m, 64);
        p2 += __shfl_xor(p2, m, 64);
      }
      if (d == 0){ emi[i] = p1; emj[i] = p2; }
    }
    LAG_TAIL(ctr);
    return;
  }

  // ----- xl part: data @ lin_w via MFMA 16x16x32 bf16 -----
  const int m = lane & 15, quad = lane >> 4;
  short8 B[4][2];
  #pragma unroll
  for (int ct = 0; ct < 4; ++ct)
    #pragma unroll
    for (int kc = 0; kc < 2; ++kc)
      #pragma unroll
      for (int j = 0; j < 8; ++j)
        B[ct][kc][j] = f2b(lin_w[(kc*32 + quad*8 + j)*64 + ct*16 + m]);

  const int rw = (blockIdx.x - 256)*64 + w*16;  // 1024 blocks x 64 rows
  short8 A0, A1;
  {
    const float4* ap0 = (const float4*)(data + (size_t)(rw + m)*64 + quad*8);
    float4 q0 = ap0[0], q1 = ap0[1];
    A0[0]=f2b(q0.x); A0[1]=f2b(q0.y); A0[2]=f2b(q0.z); A0[3]=f2b(q0.w);
    A0[4]=f2b(q1.x); A0[5]=f2b(q1.y); A0[6]=f2b(q1.z); A0[7]=f2b(q1.w);
    const float4* ap1 = (const float4*)(data + (size_t)(rw + m)*64 + 32 + quad*8);
    float4 q2 = ap1[0], q3 = ap1[1];
    A1[0]=f2b(q2.x); A1[1]=f2b(q2.y); A1[2]=f2b(q2.z); A1[3]=f2b(q2.w);
    A1[4]=f2b(q3.x); A1[5]=f2b(q3.y); A1[6]=f2b(q3.z); A1[7]=f2b(q3.w);
  }
  floatx4 acc[4];
  #pragma unroll
  for (int ct = 0; ct < 4; ++ct){
    floatx4 z = {0.f, 0.f, 0.f, 0.f};
    acc[ct] = __builtin_amdgcn_mfma_f32_16x16x32_bf16(A0, B[ct][0], z, 0, 0, 0);
    acc[ct] = __builtin_amdgcn_mfma_f32_16x16x32_bf16(A1, B[ct][1], acc[ct], 0, 0, 0);
  }
  float p1[4] = {0.f,0.f,0.f,0.f}, p2[4] = {0.f,0.f,0.f,0.f};
  #pragma unroll
  for (int ct = 0; ct < 4; ++ct){
    const float wi = att_i[ct*16 + m], wj = att_j[ct*16 + m];
    #pragma unroll
    for (int reg = 0; reg < 4; ++reg){
      float v = acc[ct][reg];
      const int row = rw + quad*4 + reg;
      xl[(size_t)row*64 + ct*16 + m] = __float2bfloat16(v);
      p1[reg] = fmaf(v, wi, p1[reg]);
      p2[reg] = fmaf(v, wj, p2[reg]);
    }
  }
  #pragma unroll
  for (int reg = 0; reg < 4; ++reg){
    #pragma unroll
    for (int s = 1; s < 16; s <<= 1){
      p1[reg] += __shfl_xor(p1[reg], s, 16);
      p2[reg] += __shfl_xor(p2[reg], s, 16);
    }
    if (m == 0){
      const int r = rw + quad*4 + reg;
      aip[r] = p1[reg];                      // emi/emj added in k_attn_agg
      ajp[r] = p2[reg];
    }
  }
  LAG_TAIL(ctr);
}

// ---------------- K2: edge softmax + gather aggregation (bf16 agg out) + bn1 shadow stats ----------------
__global__ void __launch_bounds__(256) k_attn_agg(const int* __restrict__ topk,
                         const __hip_bfloat16* __restrict__ xl,
                         fpc aip, fpc ajp, fpc emi_g, fpc emj_g, fpc gnn_bias,
                         __hip_bfloat16* __restrict__ agg, float* __restrict__ bnsum,
                         int* __restrict__ ctr){
  __shared__ float s_alpha[4][32];
  __shared__ int   s_src[4][32];
  __shared__ float s_ps[4][64], s_pq[4][64];
  const int t = threadIdx.x, w = t >> 6, lane = t & 63;
  const float bias = gnn_bias[lane];
  const int vbase = blockIdx.x*64 + w*16;    // 1024 blocks x 64 nodes; 16/wave
  float sum = 0.f, sq = 0.f;
  for (int j = 0; j < 16; ++j){
    const int v = vbase + j, i = v & 255, b = v >> 8;
    float lg = -1e30f; int sl = 0;
    if (lane < 21){
      sl = (lane < 20) ? topk[i*TK + lane] : i;
      if (lane == 20 || sl != i){            // remove_self_loops, keep appended loop
        float l = aip[v] + emi_g[i] + ajp[b*256 + sl] + emj_g[sl];
        lg = (l >= 0.f) ? l : 0.2f*l;        // leaky_relu(0.2)
      }
    }
    float m = lg;
    for (int s = 1; s < 32; s <<= 1) m = fmaxf(m, __shfl_xor(m, s, 32));
    float e = (lg > -1e29f) ? __expf(lg - m) : 0.f;
    float den = e;
    for (int s = 1; s < 32; s <<= 1) den += __shfl_xor(den, s, 32);
    if (lane < 21){ s_alpha[w][lane] = e / den; s_src[w][lane] = b*256 + sl; }
    float acc = bias;
    #pragma unroll
    for (int k = 0; k < 21; ++k)
      acc = fmaf(s_alpha[w][k], __bfloat162float(xl[(size_t)s_src[w][k]*64 + lane]), acc);
    agg[(size_t)v*64 + lane] = __float2bfloat16(acc);
    sum += acc; sq = fmaf(acc, acc, sq);
  }
  s_ps[w][lane] = sum; s_pq[w][lane] = sq;
  __syncthreads();
  if (t < 64){
    const int cp = (blockIdx.x & 7)*64;
    atomicAdd(&bnsum[cp + t],       s_ps[0][t] + s_ps[1][t] + s_ps[2][t] + s_ps[3][t]);
    atomicAdd(&bnsum[512 + cp + t], s_pq[0][t] + s_pq[1][t] + s_pq[2][t] + s_pq[3][t]);
  }
  LAG_TAIL(ctr);
}

// ---------------- K3: block-range split -- enc MFMA (blocks 0..255) | bn2 stats (256..2303) ----------------
__global__ void __launch_bounds__(256) k_encst(const __hip_bfloat16* __restrict__ agg, fpc enc_w,
                         fpc emb, fpc g1, fpc be1,
                         float* __restrict__ bnsum, float* __restrict__ part,
                         int* __restrict__ ctr){
  const int t = threadIdx.x;

  if (blockIdx.x < 256){
    // ===== enc path (round-11 no-spill shape): kt in [0,128), bt in [0,2) =====
    const int w = t >> 6, lane = t & 63;
    const int m = lane & 15, quad = lane >> 4;
    const int kt = blockIdx.x & 127, bt = blockIdx.x >> 7, kbase = kt*128;
    float scA[8], shA[8], scB[8], shB[8];
    #pragma unroll
    for (int j = 0; j < 8; ++j){
      #pragma unroll
      for (int par = 0; par < 2; ++par){
        const int d = par*32 + quad*8 + j;
        float S = 0.f, Q = 0.f;
        #pragma unroll
        for (int cp = 0; cp < 8; ++cp){ S += bnsum[cp*64 + d]; Q += bnsum[512 + cp*64 + d]; }
        float mean = S * (1.f/BN);
        float var  = Q * (1.f/BN) - mean*mean;
        float sc = g1[d] * rsqrtf(var + 1e-5f);
        float sh = be1[d] - mean*sc;
        if (par == 0){ scA[j] = sc; shA[j] = sh; } else { scB[j] = sc; shB[j] = sh; }
      }
    }
    floatx4 acc[2][4];
    #pragma unroll
    for (int i = 0; i < 2; ++i)
      #pragma unroll
      for (int ct = 0; ct < 4; ++ct)
        acc[i][ct] = (floatx4){0.f, 0.f, 0.f, 0.f};

    #pragma unroll
    for (int kc = 0; kc < 4; ++kc){
      const int kof = kbase + kc*32 + quad*8;
      const bool odd = (kc & 1);
      short8 Bf[4];
      #pragma unroll
      for (int ct = 0; ct < 4; ++ct)
        #pragma unroll
        for (int j = 0; j < 8; ++j)
          Bf[ct][j] = f2b(enc_w[(size_t)(kof + j)*64 + ct*16 + m]);
      #pragma unroll
      for (int i = 0; i < 2; ++i){
        const int row = bt*128 + (w*2 + i)*16 + m;
        uint4 uu = *(const uint4*)((const unsigned short*)agg + (size_t)row*16384 + kof);
        unsigned short h[8] = {
          (unsigned short)(uu.x & 0xffff), (unsigned short)(uu.x >> 16),
          (unsigned short)(uu.y & 0xffff), (unsigned short)(uu.y >> 16),
          (unsigned short)(uu.z & 0xffff), (unsigned short)(uu.z >> 16),
          (unsigned short)(uu.w & 0xffff), (unsigned short)(uu.w >> 16) };
        short8 Af;
        if (!odd){
          #pragma unroll
          for (int j = 0; j < 8; ++j) Af[j] = f2b(fmaxf(fmaf(b2fu(h[j]), scA[j], shA[j]), 0.f));
        } else {
          #pragma unroll
          for (int j = 0; j < 8; ++j) Af[j] = f2b(fmaxf(fmaf(b2fu(h[j]), scB[j], shB[j]), 0.f));
        }
        #pragma unroll
        for (int ct = 0; ct < 4; ++ct)
          acc[i][ct] = __builtin_amdgcn_mfma_f32_16x16x32_bf16(Af, Bf[ct], acc[i][ct], 0, 0, 0);
      }
    }
    #pragma unroll
    for (int i = 0; i < 2; ++i)
      #pragma unroll
      for (int ct = 0; ct < 4; ++ct)
        #pragma unroll
        for (int reg = 0; reg < 4; ++reg){
          const int row = bt*128 + (w*2 + i)*16 + quad*4 + reg;
          part[(size_t)kt*16384 + row*64 + ct*16 + m] = acc[i][ct][reg];
        }
    LAG_TAIL(ctr);
    return;
  }

  // ===== stats path: bn2 stats over bf16 agg (2048 blocks x 32 rows) =====
  const int sb = blockIdx.x - 256;
  const int qc = t & 15, rs = t >> 4;
  float4 sc, sh;
  {
    float s[4], q[4];
    #pragma unroll
    for (int k = 0; k < 4; ++k){
      const int d = qc*4 + k;
      float S = 0.f, Q = 0.f;
      #pragma unroll
      for (int cp = 0; cp < 8; ++cp){ S += bnsum[cp*64 + d]; Q += bnsum[512 + cp*64 + d]; }
      float mean = S * (1.f/BN);
      float var  = Q * (1.f/BN) - mean*mean;
      s[k] = g1[d] * rsqrtf(var + 1e-5f);
      q[k] = be1[d] - mean*s[k];
    }
    sc = make_float4(s[0], s[1], s[2], s[3]);
    sh = make_float4(q[0], q[1], q[2], q[3]);
  }
  const float4* emb4 = (const float4*)emb;
  float4 ys = make_float4(0,0,0,0), yq = make_float4(0,0,0,0);
  const int rbase = sb*32;
  #pragma unroll
  for (int jj = 0; jj < 2; ++jj){
    const int r = rbase + jj*16 + rs;
    ushort4 u = *(const ushort4*)((const unsigned short*)agg + (size_t)r*64 + qc*4);
    float4 e = emb4[(r & 255)*16 + qc];
    float4 y;
    y.x = fmaxf(fmaf(b2fu(u.x), sc.x, sh.x), 0.f) * e.x;
    y.y = fmaxf(fmaf(b2fu(u.y), sc.y, sh.y), 0.f) * e.y;
    y.z = fmaxf(fmaf(b2fu(u.z), sc.z, sh.z), 0.f) * e.z;
    y.w = fmaxf(fmaf(b2fu(u.w), sc.w, sh.w), 0.f) * e.w;
    ys.x += y.x; ys.y += y.y; ys.z += y.z; ys.w += y.w;
    yq.x = fmaf(y.x, y.x, yq.x); yq.y = fmaf(y.y, y.y, yq.y);
    yq.z = fmaf(y.z, y.z, yq.z); yq.w = fmaf(y.w, y.w, yq.w);
  }
  __shared__ float4 s_s[16][16], s_q[16][16];
  s_s[rs][qc] = ys; s_q[rs][qc] = yq;
  __syncthreads();
  if (t < 64){
    const int qq = t >> 2, comp = t & 3;
    float S = 0.f, Q = 0.f;
    #pragma unroll
    for (int rr = 0; rr < 16; ++rr){
      S += ((const float*)&s_s[rr][qq])[comp];
      Q += ((const float*)&s_q[rr][qq])[comp];
    }
    const int cp = (sb & 7)*64;
    atomicAdd(&bnsum[1024 + cp + t], S);
    atomicAdd(&bnsum[1536 + cp + t], Q);
  }
  LAG_TAIL(ctr);
}

// ---------------- K4: block-range split -- redarr (blocks 0..255) | score (256..2303) ----------------
__global__ void __launch_bounds__(256) k_fin(const float* __restrict__ part,
                      const __hip_bfloat16* __restrict__ agg, fpc emb,
                      fpc g1, fpc be1, fpc g2, fpc be2,
                      const float* __restrict__ bnsum,
                      fpc enc_b, fpc arr_w, fpc arr_b, fpc out_w, fpc out_b,
                      float* __restrict__ out, int* __restrict__ ctr){
  const int t = threadIdx.x;

  if (blockIdx.x < 256){
    // ===== redarr path: reduce split-K partials + arrangement head =====
    __shared__ float s_enc[4][64];
    const int b = blockIdx.x, w = t >> 6, lane = t & 63;
    float s = 0.f;
    #pragma unroll 8
    for (int k = 0; k < 32; ++k)
      s += part[(size_t)(w*32 + k)*16384 + b*64 + lane];
    s_enc[w][lane] = s;
    __syncthreads();
    if (t < 64){
      float e = s_enc[0][t] + s_enc[1][t] + s_enc[2][t] + s_enc[3][t] + enc_b[t];
      float o[7];
      #pragma unroll
      for (int j = 0; j < 7; ++j) o[j] = e * arr_w[t*7 + j];
      #pragma unroll
      for (int j = 0; j < 7; ++j)
        #pragma unroll
        for (int m = 1; m < 64; m <<= 1) o[j] += __shfl_xor(o[j], m, 64);
      if (t == 0){
        #pragma unroll
        for (int j = 0; j < 7; ++j) out[65536 + b*7 + j] = o[j] + arr_b[j];
      }
    }
    LAG_TAIL(ctr);
    return;
  }

  // ===== score path =====
  const int w = t >> 6, lane = t & 63;
  const int qc = lane & 15, rq = lane >> 4;
  float sc1[4], sh1[4], sc2[4], sh2[4], ow[4];
  #pragma unroll
  for (int k = 0; k < 4; ++k){
    const int d = qc*4 + k;
    float S1 = 0.f, Q1 = 0.f, S2 = 0.f, Q2 = 0.f;
    #pragma unroll
    for (int cp = 0; cp < 8; ++cp){
      S1 += bnsum[cp*64 + d];        Q1 += bnsum[512 + cp*64 + d];
      S2 += bnsum[1024 + cp*64 + d]; Q2 += bnsum[1536 + cp*64 + d];
    }
    float m1 = S1 * (1.f/BN), v1 = Q1 * (1.f/BN) - m1*m1;
    sc1[k] = g1[d] * rsqrtf(v1 + 1e-5f);
    sh1[k] = be1[d] - m1*sc1[k];
    float m2 = S2 * (1.f/BN), v2 = Q2 * (1.f/BN) - m2*m2;
    sc2[k] = g2[d] * rsqrtf(v2 + 1e-5f);
    sh2[k] = be2[d] - m2*sc2[k];
    ow[k]  = out_w[d];
  }
  const float ob = out_b[0];
  const float4* emb4 = (const float4*)emb;
  const int base = (blockIdx.x - 256)*32 + w*8;
  #pragma unroll
  for (int it = 0; it < 2; ++it){
    const int r = base + it*4 + rq;
    ushort4 u = *(const ushort4*)((const unsigned short*)agg + (size_t)r*64 + qc*4);
    float4 e4 = emb4[(r & 255)*16 + qc];
    float p = 0.f, g, y, yh;
    g = fmaxf(fmaf(b2fu(u.x), sc1[0], sh1[0]), 0.f); y = g*e4.x;
    yh = fmaxf(fmaf(y, sc2[0], sh2[0]), 0.f); p = fmaf(yh, ow[0], p);
    g = fmaxf(fmaf(b2fu(u.y), sc1[1], sh1[1]), 0.f); y = g*e4.y;
    yh = fmaxf(fmaf(y, sc2[1], sh2[1]), 0.f); p = fmaf(yh, ow[1], p);
    g = fmaxf(fmaf(b2fu(u.z), sc1[2], sh1[2]), 0.f); y = g*e4.z;
    yh = fmaxf(fmaf(y, sc2[2], sh2[2]), 0.f); p = fmaf(yh, ow[2], p);
    g = fmaxf(fmaf(b2fu(u.w), sc1[3], sh1[3]), 0.f); y = g*e4.w;
    yh = fmaxf(fmaf(y, sc2[3], sh2[3]), 0.f); p = fmaf(yh, ow[3], p);
    #pragma unroll
    for (int mm = 1; mm < 16; mm <<= 1) p += __shfl_xor(p, mm, 16);
    if (qc == 0) out[r] = p + ob;
  }
  LAG_TAIL(ctr);
}

extern "C" void kernel_launch(void* const* d_in, const int* in_sizes, int n_in,
                              void* d_out, int out_size, void* d_ws, size_t ws_size,
                              hipStream_t stream) {
  fpc data     = (fpc)d_in[0];
  fpc emb      = (fpc)d_in[1];
  fpc lin_w    = (fpc)d_in[2];
  fpc att_i    = (fpc)d_in[3];
  fpc att_j    = (fpc)d_in[4];
  fpc att_em_i = (fpc)d_in[5];
  fpc att_em_j = (fpc)d_in[6];
  fpc gnn_bias = (fpc)d_in[7];
  fpc g1       = (fpc)d_in[8];
  fpc be1      = (fpc)d_in[9];
  fpc g2       = (fpc)d_in[10];
  fpc be2      = (fpc)d_in[11];
  fpc enc_w    = (fpc)d_in[12];
  fpc enc_b    = (fpc)d_in[13];
  fpc arr_w    = (fpc)d_in[14];
  fpc arr_b    = (fpc)d_in[15];
  fpc out_w    = (fpc)d_in[16];
  fpc out_b    = (fpc)d_in[17];

  float* fw = (float*)d_ws;
  int*   topk    = (int*)d_ws;            // [0, 5120)
  float* emi     = fw + 5120;             // 256
  float* emj     = fw + 5376;             // 256
  float* bnsum   = fw + 5632;             // 2048 shadow BN accumulators (zeroed by k_gx block 0)
  float* aip     = fw + 7680;             // 65536
  float* ajp     = fw + 73216;            // 65536
  __hip_bfloat16* agg = (__hip_bfloat16*)(fw + 138752);  // 65536*64 bf16 = 8.39 MB
  __hip_bfloat16* xl  = (__hip_bfloat16*)(fw + 2235904); // 65536*64 bf16 = 8.39 MB
  float* part    = (float*)xl;            // 128*16384 f32 = 8.39 MB, aliases dead xl
  int*   ctr     = (int*)(fw + 5000000);  // 4 lag counters, well past live data
  float* out     = (float*)d_out;

  hipMemsetAsync(ctr, 0, 4*sizeof(int), stream);

  k_gx       <<<1280,  256, 0, stream>>>(data, emb, lin_w, att_i, att_j, att_em_i, att_em_j,
                                         topk, emi, emj, xl, aip, ajp, bnsum, ctr+0);
  k_attn_agg <<<1024,  256, 0, stream>>>(topk, xl, aip, ajp, emi, emj, gnn_bias, agg, bnsum, ctr+1);
  k_encst    <<<2304,  256, 0, stream>>>(agg, enc_w, emb, g1, be1, bnsum, part, ctr+2);
  k_fin      <<<2304,  256, 0, stream>>>(part, agg, emb, g1, be1, g2, be2, bnsum,
                                         enc_b, arr_w, arr_b, out_w, out_b, out, ctr+3);
}

// Round 4
// 361.848 us; speedup vs baseline: 1.1650x; 1.1650x over previous
//
#include <hip/hip_runtime.h>
#include <hip/hip_bf16.h>

#define TK 20
#define BN 65536

typedef const float* fpc;
typedef __attribute__((ext_vector_type(8))) short short8;
typedef __attribute__((ext_vector_type(4))) float floatx4;

// f32 -> bf16 bits, round-to-nearest-even
__device__ __forceinline__ short f2b(float f){
  unsigned u = __float_as_uint(f);
  return (short)((u + 0x7fffu + ((u >> 16) & 1u)) >> 16);
}
__device__ __forceinline__ float b2fu(unsigned short u){
  return __uint_as_float(((unsigned)u) << 16);
}

// --- instrumentation (K1/K3/K4 only this round): last-finishing block spins a
// fixed cycle count so the kernel rises above harness poison-fills in top-5.
// shown_i = true_i + S, S ~= 120k cyc / 1.95GHz ~= 61.6 us (round-3 calibration).
__device__ __forceinline__ void lag_spin(unsigned long long cyc){
  unsigned long long t0 = __builtin_readcyclecounter();
  while (__builtin_readcyclecounter() - t0 < cyc) { }
}
#define LAG_TAIL(CTR) do{ \
    if (threadIdx.x == 0){ \
      int _v = atomicAdd((CTR), 1); \
      if (_v == (int)gridDim.x - 1) lag_spin(120000ULL); \
    } }while(0)

// ---------------- K1: fused graph (blocks 0..255, block 0 zeroes bnsum) + xl MFMA (256..1279) ----------------
__global__ void __launch_bounds__(256) k_gx(fpc data, fpc emb, fpc lin_w, fpc att_i, fpc att_j,
        fpc att_em_i, fpc att_em_j,
        int* __restrict__ topk, float* __restrict__ emi, float* __restrict__ emj,
        __hip_bfloat16* __restrict__ xl, float* __restrict__ aip, float* __restrict__ ajp,
        float* __restrict__ bnsum, int* __restrict__ ctr){
  __shared__ float s_cos[256];
  __shared__ float s_wi[64];
  const int t = threadIdx.x, w = t >> 6, lane = t & 63;

  if (blockIdx.x < 256){
    if (blockIdx.x == 0){
      #pragma unroll
      for (int i = 0; i < 8; ++i) bnsum[t + i*256] = 0.f;   // zero shadow BN accumulators
    }
    // ----- graph part: top-20 cosine + emi/emj -----
    const int i = blockIdx.x;
    if (t < 64) s_wi[t] = emb[i*64 + t];
    __syncthreads();
    float dot = 0.f, nj = 0.f, ni = 0.f;
    for (int f = 0; f < 64; ++f){
      float wj = emb[t*64 + f], wi = s_wi[f];
      dot = fmaf(wi, wj, dot); nj = fmaf(wj, wj, nj); ni = fmaf(wi, wi, ni);
    }
    s_cos[t] = dot / (sqrtf(ni) * sqrtf(nj));
    __syncthreads();
    if (t < 64){
      float v0 = s_cos[t], v1 = s_cos[t+64], v2 = s_cos[t+128], v3 = s_cos[t+192];
      int taken = 0;
      for (int r = 0; r < TK; ++r){
        float bv = (taken & 1) ? -3.f : v0; int bi = t;
        float c;
        c = (taken & 2) ? -3.f : v1; if (c > bv){ bv = c; bi = t+64;  }
        c = (taken & 4) ? -3.f : v2; if (c > bv){ bv = c; bi = t+128; }
        c = (taken & 8) ? -3.f : v3; if (c > bv){ bv = c; bi = t+192; }
        for (int m = 1; m < 64; m <<= 1){
          float ov = __shfl_xor(bv, m, 64);
          int   oi = __shfl_xor(bi, m, 64);
          if (ov > bv || (ov == bv && oi < bi)){ bv = ov; bi = oi; }
        }
        if (t == 0) topk[i*TK + r] = bi;
        if ((bi & 63) == t) taken |= 1 << (bi >> 6);
      }
    } else if (t < 128){
      int d = t - 64;
      float wv = s_wi[d];
      float p1 = wv * att_em_i[d];
      float p2 = wv * att_em_j[d];
      for (int m = 1; m < 64; m <<= 1){
        p1 += __shfl_xor(p1, m, 64);
        p2 += __shfl_xor(p2, m, 64);
      }
      if (d == 0){ emi[i] = p1; emj[i] = p2; }
    }
    LAG_TAIL(ctr);
    return;
  }

  // ----- xl part: data @ lin_w via MFMA 16x16x32 bf16 -----
  const int m = lane & 15, quad = lane >> 4;
  short8 B[4][2];
  #pragma unroll
  for (int ct = 0; ct < 4; ++ct)
    #pragma unroll
    for (int kc = 0; kc < 2; ++kc)
      #pragma unroll
      for (int j = 0; j < 8; ++j)
        B[ct][kc][j] = f2b(lin_w[(kc*32 + quad*8 + j)*64 + ct*16 + m]);

  const int rw = (blockIdx.x - 256)*64 + w*16;  // 1024 blocks x 64 rows
  short8 A0, A1;
  {
    const float4* ap0 = (const float4*)(data + (size_t)(rw + m)*64 + quad*8);
    float4 q0 = ap0[0], q1 = ap0[1];
    A0[0]=f2b(q0.x); A0[1]=f2b(q0.y); A0[2]=f2b(q0.z); A0[3]=f2b(q0.w);
    A0[4]=f2b(q1.x); A0[5]=f2b(q1.y); A0[6]=f2b(q1.z); A0[7]=f2b(q1.w);
    const float4* ap1 = (const float4*)(data + (size_t)(rw + m)*64 + 32 + quad*8);
    float4 q2 = ap1[0], q3 = ap1[1];
    A1[0]=f2b(q2.x); A1[1]=f2b(q2.y); A1[2]=f2b(q2.z); A1[3]=f2b(q2.w);
    A1[4]=f2b(q3.x); A1[5]=f2b(q3.y); A1[6]=f2b(q3.z); A1[7]=f2b(q3.w);
  }
  floatx4 acc[4];
  #pragma unroll
  for (int ct = 0; ct < 4; ++ct){
    floatx4 z = {0.f, 0.f, 0.f, 0.f};
    acc[ct] = __builtin_amdgcn_mfma_f32_16x16x32_bf16(A0, B[ct][0], z, 0, 0, 0);
    acc[ct] = __builtin_amdgcn_mfma_f32_16x16x32_bf16(A1, B[ct][1], acc[ct], 0, 0, 0);
  }
  float p1[4] = {0.f,0.f,0.f,0.f}, p2[4] = {0.f,0.f,0.f,0.f};
  #pragma unroll
  for (int ct = 0; ct < 4; ++ct){
    const float wi = att_i[ct*16 + m], wj = att_j[ct*16 + m];
    #pragma unroll
    for (int reg = 0; reg < 4; ++reg){
      float v = acc[ct][reg];
      const int row = rw + quad*4 + reg;
      xl[(size_t)row*64 + ct*16 + m] = __float2bfloat16(v);
      p1[reg] = fmaf(v, wi, p1[reg]);
      p2[reg] = fmaf(v, wj, p2[reg]);
    }
  }
  #pragma unroll
  for (int reg = 0; reg < 4; ++reg){
    #pragma unroll
    for (int s = 1; s < 16; s <<= 1){
      p1[reg] += __shfl_xor(p1[reg], s, 16);
      p2[reg] += __shfl_xor(p2[reg], s, 16);
    }
    if (m == 0){
      const int r = rw + quad*4 + reg;
      aip[r] = p1[reg];                      // emi/emj added in k_attn_agg
      ajp[r] = p2[reg];
    }
  }
  LAG_TAIL(ctr);
}

// ---------------- K2 (rebuilt): dual-node softmax + shuffle-broadcast aggregation ----------------
// 2048 blocks x 32 nodes (8/wave, 2 per iteration -> 4 short chains). No LDS
// round-trip in the inner loop: alpha broadcast via __shfl (register-renamed,
// so iterations pipeline), src via uniform-address LDS broadcast of s_topk.
__global__ void __launch_bounds__(256) k_attn_agg(const int* __restrict__ topk,
                         const __hip_bfloat16* __restrict__ xl,
                         fpc aip, fpc ajp, fpc emi_g, fpc emj_g, fpc gnn_bias,
                         __hip_bfloat16* __restrict__ agg, float* __restrict__ bnsum){
  __shared__ int   s_topk[32*TK];           // 2.5 KB
  __shared__ float s_ai[32];                // aip[v] + emi[i]
  __shared__ float s_aj[256];               // ajp[b*256+k] + emj[k]
  __shared__ float s_ps[4][64], s_pq[4][64];
  const int t = threadIdx.x, w = t >> 6, lane = t & 63;
  const int b  = blockIdx.x >> 3;           // batch (8 blocks per batch)
  const int i0 = (blockIdx.x & 7) * 32;     // first node id within batch

  // ----- staging (coalesced, tiny) -----
  for (int x = t; x < 32*TK; x += 256) s_topk[x] = topk[i0*TK + x];
  s_aj[t] = ajp[b*256 + t] + emj_g[t];
  if (t < 32) s_ai[t] = aip[blockIdx.x*32 + t] + emi_g[i0 + t];
  __syncthreads();

  const float bias = gnn_bias[lane];
  const int k32 = lane & 31, half = lane >> 5;
  const __hip_bfloat16* xb = xl + (size_t)b*16384;   // batch-b xl slice [256][64]
  float sum = 0.f, sq = 0.f;
  #pragma unroll
  for (int j = 0; j < 4; ++j){
    const int nA = w*8 + j*2;               // local node for half 0
    const int nloc = nA + half;             // this half's node
    const int i = i0 + nloc;
    // dual width-32 softmax over 21 edges
    float lg = -1e30f;
    if (k32 < 21){
      int sl = (k32 < 20) ? s_topk[nloc*TK + k32] : i;
      if (k32 == 20 || sl != i){            // remove_self_loops, keep appended loop
        float l = s_ai[nloc] + s_aj[sl];
        lg = (l >= 0.f) ? l : 0.2f*l;       // leaky_relu(0.2)
      }
    }
    float m = lg;
    for (int s = 1; s < 32; s <<= 1) m = fmaxf(m, __shfl_xor(m, s, 32));
    float e = (lg > -1e29f) ? __expf(lg - m) : 0.f;
    float den = e;
    for (int s = 1; s < 32; s <<= 1) den += __shfl_xor(den, s, 32);
    const float alpha = e / den;
    // aggregation for both nodes; alpha via shuffle, src via LDS broadcast
    const int iA = i0 + nA, iB = iA + 1;
    float accA = bias, accB = bias;
    #pragma unroll
    for (int k = 0; k < 21; ++k){
      const float aA = __shfl(alpha, k, 64);
      const float aB = __shfl(alpha, 32 + k, 64);
      const int rA = (k < 20) ? s_topk[nA*TK + k]     : iA;
      const int rB = (k < 20) ? s_topk[(nA+1)*TK + k] : iB;
      accA = fmaf(aA, __bfloat162float(xb[(size_t)rA*64 + lane]), accA);
      accB = fmaf(aB, __bfloat162float(xb[(size_t)rB*64 + lane]), accB);
    }
    const size_t vA = (size_t)blockIdx.x*32 + nA;
    agg[vA*64 + lane]     = __float2bfloat16(accA);
    agg[(vA+1)*64 + lane] = __float2bfloat16(accB);
    sum += accA + accB;
    sq = fmaf(accA, accA, fmaf(accB, accB, sq));
  }
  s_ps[w][lane] = sum; s_pq[w][lane] = sq;
  __syncthreads();
  if (t < 64){
    const int cp = (blockIdx.x & 7)*64;
    atomicAdd(&bnsum[cp + t],       s_ps[0][t] + s_ps[1][t] + s_ps[2][t] + s_ps[3][t]);
    atomicAdd(&bnsum[512 + cp + t], s_pq[0][t] + s_pq[1][t] + s_pq[2][t] + s_pq[3][t]);
  }
}

// ---------------- K3: block-range split -- enc MFMA (blocks 0..255) | bn2 stats (256..2303) ----------------
__global__ void __launch_bounds__(256) k_encst(const __hip_bfloat16* __restrict__ agg, fpc enc_w,
                         fpc emb, fpc g1, fpc be1,
                         float* __restrict__ bnsum, float* __restrict__ part,
                         int* __restrict__ ctr){
  const int t = threadIdx.x;

  if (blockIdx.x < 256){
    // ===== enc path (round-11 no-spill shape): kt in [0,128), bt in [0,2) =====
    const int w = t >> 6, lane = t & 63;
    const int m = lane & 15, quad = lane >> 4;
    const int kt = blockIdx.x & 127, bt = blockIdx.x >> 7, kbase = kt*128;
    float scA[8], shA[8], scB[8], shB[8];
    #pragma unroll
    for (int j = 0; j < 8; ++j){
      #pragma unroll
      for (int par = 0; par < 2; ++par){
        const int d = par*32 + quad*8 + j;
        float S = 0.f, Q = 0.f;
        #pragma unroll
        for (int cp = 0; cp < 8; ++cp){ S += bnsum[cp*64 + d]; Q += bnsum[512 + cp*64 + d]; }
        float mean = S * (1.f/BN);
        float var  = Q * (1.f/BN) - mean*mean;
        float sc = g1[d] * rsqrtf(var + 1e-5f);
        float sh = be1[d] - mean*sc;
        if (par == 0){ scA[j] = sc; shA[j] = sh; } else { scB[j] = sc; shB[j] = sh; }
      }
    }
    floatx4 acc[2][4];
    #pragma unroll
    for (int i = 0; i < 2; ++i)
      #pragma unroll
      for (int ct = 0; ct < 4; ++ct)
        acc[i][ct] = (floatx4){0.f, 0.f, 0.f, 0.f};

    #pragma unroll
    for (int kc = 0; kc < 4; ++kc){
      const int kof = kbase + kc*32 + quad*8;
      const bool odd = (kc & 1);
      short8 Bf[4];
      #pragma unroll
      for (int ct = 0; ct < 4; ++ct)
        #pragma unroll
        for (int j = 0; j < 8; ++j)
          Bf[ct][j] = f2b(enc_w[(size_t)(kof + j)*64 + ct*16 + m]);
      #pragma unroll
      for (int i = 0; i < 2; ++i){
        const int row = bt*128 + (w*2 + i)*16 + m;
        uint4 uu = *(const uint4*)((const unsigned short*)agg + (size_t)row*16384 + kof);
        unsigned short h[8] = {
          (unsigned short)(uu.x & 0xffff), (unsigned short)(uu.x >> 16),
          (unsigned short)(uu.y & 0xffff), (unsigned short)(uu.y >> 16),
          (unsigned short)(uu.z & 0xffff), (unsigned short)(uu.z >> 16),
          (unsigned short)(uu.w & 0xffff), (unsigned short)(uu.w >> 16) };
        short8 Af;
        if (!odd){
          #pragma unroll
          for (int j = 0; j < 8; ++j) Af[j] = f2b(fmaxf(fmaf(b2fu(h[j]), scA[j], shA[j]), 0.f));
        } else {
          #pragma unroll
          for (int j = 0; j < 8; ++j) Af[j] = f2b(fmaxf(fmaf(b2fu(h[j]), scB[j], shB[j]), 0.f));
        }
        #pragma unroll
        for (int ct = 0; ct < 4; ++ct)
          acc[i][ct] = __builtin_amdgcn_mfma_f32_16x16x32_bf16(Af, Bf[ct], acc[i][ct], 0, 0, 0);
      }
    }
    #pragma unroll
    for (int i = 0; i < 2; ++i)
      #pragma unroll
      for (int ct = 0; ct < 4; ++ct)
        #pragma unroll
        for (int reg = 0; reg < 4; ++reg){
          const int row = bt*128 + (w*2 + i)*16 + quad*4 + reg;
          part[(size_t)kt*16384 + row*64 + ct*16 + m] = acc[i][ct][reg];
        }
    LAG_TAIL(ctr);
    return;
  }

  // ===== stats path: bn2 stats over bf16 agg (2048 blocks x 32 rows) =====
  const int sb = blockIdx.x - 256;
  const int qc = t & 15, rs = t >> 4;
  float4 sc, sh;
  {
    float s[4], q[4];
    #pragma unroll
    for (int k = 0; k < 4; ++k){
      const int d = qc*4 + k;
      float S = 0.f, Q = 0.f;
      #pragma unroll
      for (int cp = 0; cp < 8; ++cp){ S += bnsum[cp*64 + d]; Q += bnsum[512 + cp*64 + d]; }
      float mean = S * (1.f/BN);
      float var  = Q * (1.f/BN) - mean*mean;
      s[k] = g1[d] * rsqrtf(var + 1e-5f);
      q[k] = be1[d] - mean*s[k];
    }
    sc = make_float4(s[0], s[1], s[2], s[3]);
    sh = make_float4(q[0], q[1], q[2], q[3]);
  }
  const float4* emb4 = (const float4*)emb;
  float4 ys = make_float4(0,0,0,0), yq = make_float4(0,0,0,0);
  const int rbase = sb*32;
  #pragma unroll
  for (int jj = 0; jj < 2; ++jj){
    const int r = rbase + jj*16 + rs;
    ushort4 u = *(const ushort4*)((const unsigned short*)agg + (size_t)r*64 + qc*4);
    float4 e = emb4[(r & 255)*16 + qc];
    float4 y;
    y.x = fmaxf(fmaf(b2fu(u.x), sc.x, sh.x), 0.f) * e.x;
    y.y = fmaxf(fmaf(b2fu(u.y), sc.y, sh.y), 0.f) * e.y;
    y.z = fmaxf(fmaf(b2fu(u.z), sc.z, sh.z), 0.f) * e.z;
    y.w = fmaxf(fmaf(b2fu(u.w), sc.w, sh.w), 0.f) * e.w;
    ys.x += y.x; ys.y += y.y; ys.z += y.z; ys.w += y.w;
    yq.x = fmaf(y.x, y.x, yq.x); yq.y = fmaf(y.y, y.y, yq.y);
    yq.z = fmaf(y.z, y.z, yq.z); yq.w = fmaf(y.w, y.w, yq.w);
  }
  __shared__ float4 s_s[16][16], s_q[16][16];
  s_s[rs][qc] = ys; s_q[rs][qc] = yq;
  __syncthreads();
  if (t < 64){
    const int qq = t >> 2, comp = t & 3;
    float S = 0.f, Q = 0.f;
    #pragma unroll
    for (int rr = 0; rr < 16; ++rr){
      S += ((const float*)&s_s[rr][qq])[comp];
      Q += ((const float*)&s_q[rr][qq])[comp];
    }
    const int cp = (sb & 7)*64;
    atomicAdd(&bnsum[1024 + cp + t], S);
    atomicAdd(&bnsum[1536 + cp + t], Q);
  }
  LAG_TAIL(ctr);
}

// ---------------- K4: block-range split -- redarr (blocks 0..255) | score (256..2303) ----------------
__global__ void __launch_bounds__(256) k_fin(const float* __restrict__ part,
                      const __hip_bfloat16* __restrict__ agg, fpc emb,
                      fpc g1, fpc be1, fpc g2, fpc be2,
                      const float* __restrict__ bnsum,
                      fpc enc_b, fpc arr_w, fpc arr_b, fpc out_w, fpc out_b,
                      float* __restrict__ out, int* __restrict__ ctr){
  const int t = threadIdx.x;

  if (blockIdx.x < 256){
    // ===== redarr path: reduce split-K partials + arrangement head =====
    __shared__ float s_enc[4][64];
    const int b = blockIdx.x, w = t >> 6, lane = t & 63;
    float s = 0.f;
    #pragma unroll 8
    for (int k = 0; k < 32; ++k)
      s += part[(size_t)(w*32 + k)*16384 + b*64 + lane];
    s_enc[w][lane] = s;
    __syncthreads();
    if (t < 64){
      float e = s_enc[0][t] + s_enc[1][t] + s_enc[2][t] + s_enc[3][t] + enc_b[t];
      float o[7];
      #pragma unroll
      for (int j = 0; j < 7; ++j) o[j] = e * arr_w[t*7 + j];
      #pragma unroll
      for (int j = 0; j < 7; ++j)
        #pragma unroll
        for (int m = 1; m < 64; m <<= 1) o[j] += __shfl_xor(o[j], m, 64);
      if (t == 0){
        #pragma unroll
        for (int j = 0; j < 7; ++j) out[65536 + b*7 + j] = o[j] + arr_b[j];
      }
    }
    LAG_TAIL(ctr);
    return;
  }

  // ===== score path =====
  const int w = t >> 6, lane = t & 63;
  const int qc = lane & 15, rq = lane >> 4;
  float sc1[4], sh1[4], sc2[4], sh2[4], ow[4];
  #pragma unroll
  for (int k = 0; k < 4; ++k){
    const int d = qc*4 + k;
    float S1 = 0.f, Q1 = 0.f, S2 = 0.f, Q2 = 0.f;
    #pragma unroll
    for (int cp = 0; cp < 8; ++cp){
      S1 += bnsum[cp*64 + d];        Q1 += bnsum[512 + cp*64 + d];
      S2 += bnsum[1024 + cp*64 + d]; Q2 += bnsum[1536 + cp*64 + d];
    }
    float m1 = S1 * (1.f/BN), v1 = Q1 * (1.f/BN) - m1*m1;
    sc1[k] = g1[d] * rsqrtf(v1 + 1e-5f);
    sh1[k] = be1[d] - m1*sc1[k];
    float m2 = S2 * (1.f/BN), v2 = Q2 * (1.f/BN) - m2*m2;
    sc2[k] = g2[d] * rsqrtf(v2 + 1e-5f);
    sh2[k] = be2[d] - m2*sc2[k];
    ow[k]  = out_w[d];
  }
  const float ob = out_b[0];
  const float4* emb4 = (const float4*)emb;
  const int base = (blockIdx.x - 256)*32 + w*8;
  #pragma unroll
  for (int it = 0; it < 2; ++it){
    const int r = base + it*4 + rq;
    ushort4 u = *(const ushort4*)((const unsigned short*)agg + (size_t)r*64 + qc*4);
    float4 e4 = emb4[(r & 255)*16 + qc];
    float p = 0.f, g, y, yh;
    g = fmaxf(fmaf(b2fu(u.x), sc1[0], sh1[0]), 0.f); y = g*e4.x;
    yh = fmaxf(fmaf(y, sc2[0], sh2[0]), 0.f); p = fmaf(yh, ow[0], p);
    g = fmaxf(fmaf(b2fu(u.y), sc1[1], sh1[1]), 0.f); y = g*e4.y;
    yh = fmaxf(fmaf(y, sc2[1], sh2[1]), 0.f); p = fmaf(yh, ow[1], p);
    g = fmaxf(fmaf(b2fu(u.z), sc1[2], sh1[2]), 0.f); y = g*e4.z;
    yh = fmaxf(fmaf(y, sc2[2], sh2[2]), 0.f); p = fmaf(yh, ow[2], p);
    g = fmaxf(fmaf(b2fu(u.w), sc1[3], sh1[3]), 0.f); y = g*e4.w;
    yh = fmaxf(fmaf(y, sc2[3], sh2[3]), 0.f); p = fmaf(yh, ow[3], p);
    #pragma unroll
    for (int mm = 1; mm < 16; mm <<= 1) p += __shfl_xor(p, mm, 16);
    if (qc == 0) out[r] = p + ob;
  }
  LAG_TAIL(ctr);
}

extern "C" void kernel_launch(void* const* d_in, const int* in_sizes, int n_in,
                              void* d_out, int out_size, void* d_ws, size_t ws_size,
                              hipStream_t stream) {
  fpc data     = (fpc)d_in[0];
  fpc emb      = (fpc)d_in[1];
  fpc lin_w    = (fpc)d_in[2];
  fpc att_i    = (fpc)d_in[3];
  fpc att_j    = (fpc)d_in[4];
  fpc att_em_i = (fpc)d_in[5];
  fpc att_em_j = (fpc)d_in[6];
  fpc gnn_bias = (fpc)d_in[7];
  fpc g1       = (fpc)d_in[8];
  fpc be1      = (fpc)d_in[9];
  fpc g2       = (fpc)d_in[10];
  fpc be2      = (fpc)d_in[11];
  fpc enc_w    = (fpc)d_in[12];
  fpc enc_b    = (fpc)d_in[13];
  fpc arr_w    = (fpc)d_in[14];
  fpc arr_b    = (fpc)d_in[15];
  fpc out_w    = (fpc)d_in[16];
  fpc out_b    = (fpc)d_in[17];

  float* fw = (float*)d_ws;
  int*   topk    = (int*)d_ws;            // [0, 5120)
  float* emi     = fw + 5120;             // 256
  float* emj     = fw + 5376;             // 256
  float* bnsum   = fw + 5632;             // 2048 shadow BN accumulators (zeroed by k_gx block 0)
  float* aip     = fw + 7680;             // 65536
  float* ajp     = fw + 73216;            // 65536
  __hip_bfloat16* agg = (__hip_bfloat16*)(fw + 138752);  // 65536*64 bf16 = 8.39 MB
  __hip_bfloat16* xl  = (__hip_bfloat16*)(fw + 2235904); // 65536*64 bf16 = 8.39 MB
  float* part    = (float*)xl;            // 128*16384 f32 = 8.39 MB, aliases dead xl
  int*   ctr     = (int*)(fw + 5000000);  // lag counters, well past live data
  float* out     = (float*)d_out;

  hipMemsetAsync(ctr, 0, 4*sizeof(int), stream);

  k_gx       <<<1280,  256, 0, stream>>>(data, emb, lin_w, att_i, att_j, att_em_i, att_em_j,
                                         topk, emi, emj, xl, aip, ajp, bnsum, ctr+0);
  k_attn_agg <<<2048,  256, 0, stream>>>(topk, xl, aip, ajp, emi, emj, gnn_bias, agg, bnsum);
  k_encst    <<<2304,  256, 0, stream>>>(agg, enc_w, emb, g1, be1, bnsum, part, ctr+2);
  k_fin      <<<2304,  256, 0, stream>>>(part, agg, emb, g1, be1, g2, be2, bnsum,
                                         enc_b, arr_w, arr_b, out_w, out_b, out, ctr+3);
}

// Round 5
// 355.881 us; speedup vs baseline: 1.1845x; 1.0168x over previous
//
#include <hip/hip_runtime.h>
#include <hip/hip_bf16.h>

#define TK 20
#define BN 65536

typedef const float* fpc;
typedef __attribute__((ext_vector_type(8))) short short8;
typedef __attribute__((ext_vector_type(4))) float floatx4;

// f32 -> bf16 bits, round-to-nearest-even
__device__ __forceinline__ short f2b(float f){
  unsigned u = __float_as_uint(f);
  return (short)((u + 0x7fffu + ((u >> 16) & 1u)) >> 16);
}
__device__ __forceinline__ float b2fu(unsigned short u){
  return __uint_as_float(((unsigned)u) << 16);
}

// --- instrumentation (K1/K3/K4): last-finishing block spins a fixed cycle count
// so the kernel rises above harness poison-fills in top-5 with full counters.
// shown_i = true_i + S, S ~= 120k cyc / 1.95GHz ~= 61.6us (round-3 calibration).
__device__ __forceinline__ void lag_spin(unsigned long long cyc){
  unsigned long long t0 = __builtin_readcyclecounter();
  while (__builtin_readcyclecounter() - t0 < cyc) { }
}
#define LAG_TAIL(CTR) do{ \
    if (threadIdx.x == 0){ \
      int _v = atomicAdd((CTR), 1); \
      if (_v == (int)gridDim.x - 1) lag_spin(120000ULL); \
    } }while(0)

// ---------------- K1: fused graph (blocks 0..255, block 0 zeroes bnsum) + xl MFMA (256..1279) ----------------
__global__ void __launch_bounds__(256) k_gx(fpc data, fpc emb, fpc lin_w, fpc att_i, fpc att_j,
        fpc att_em_i, fpc att_em_j,
        int* __restrict__ topk, float* __restrict__ emi, float* __restrict__ emj,
        __hip_bfloat16* __restrict__ xl, float* __restrict__ aip, float* __restrict__ ajp,
        float* __restrict__ bnsum, int* __restrict__ ctr){
  __shared__ float s_cos[256];
  __shared__ float s_wi[64];
  const int t = threadIdx.x, w = t >> 6, lane = t & 63;

  if (blockIdx.x < 256){
    if (blockIdx.x == 0){
      #pragma unroll
      for (int i = 0; i < 8; ++i) bnsum[t + i*256] = 0.f;   // zero shadow BN accumulators
    }
    // ----- graph part: top-20 cosine + emi/emj -----
    const int i = blockIdx.x;
    if (t < 64) s_wi[t] = emb[i*64 + t];
    __syncthreads();
    float dot = 0.f, nj = 0.f, ni = 0.f;
    for (int f = 0; f < 64; ++f){
      float wj = emb[t*64 + f], wi = s_wi[f];
      dot = fmaf(wi, wj, dot); nj = fmaf(wj, wj, nj); ni = fmaf(wi, wi, ni);
    }
    s_cos[t] = dot / (sqrtf(ni) * sqrtf(nj));
    __syncthreads();
    if (t < 64){
      float v0 = s_cos[t], v1 = s_cos[t+64], v2 = s_cos[t+128], v3 = s_cos[t+192];
      int taken = 0;
      for (int r = 0; r < TK; ++r){
        float bv = (taken & 1) ? -3.f : v0; int bi = t;
        float c;
        c = (taken & 2) ? -3.f : v1; if (c > bv){ bv = c; bi = t+64;  }
        c = (taken & 4) ? -3.f : v2; if (c > bv){ bv = c; bi = t+128; }
        c = (taken & 8) ? -3.f : v3; if (c > bv){ bv = c; bi = t+192; }
        for (int m = 1; m < 64; m <<= 1){
          float ov = __shfl_xor(bv, m, 64);
          int   oi = __shfl_xor(bi, m, 64);
          if (ov > bv || (ov == bv && oi < bi)){ bv = ov; bi = oi; }
        }
        if (t == 0) topk[i*TK + r] = bi;
        if ((bi & 63) == t) taken |= 1 << (bi >> 6);
      }
    } else if (t < 128){
      int d = t - 64;
      float wv = s_wi[d];
      float p1 = wv * att_em_i[d];
      float p2 = wv * att_em_j[d];
      for (int m = 1; m < 64; m <<= 1){
        p1 += __shfl_xor(p1, m, 64);
        p2 += __shfl_xor(p2, m, 64);
      }
      if (d == 0){ emi[i] = p1; emj[i] = p2; }
    }
    LAG_TAIL(ctr);
    return;
  }

  // ----- xl part: data @ lin_w via MFMA 16x16x32 bf16 -----
  const int m = lane & 15, quad = lane >> 4;
  short8 B[4][2];
  #pragma unroll
  for (int ct = 0; ct < 4; ++ct)
    #pragma unroll
    for (int kc = 0; kc < 2; ++kc)
      #pragma unroll
      for (int j = 0; j < 8; ++j)
        B[ct][kc][j] = f2b(lin_w[(kc*32 + quad*8 + j)*64 + ct*16 + m]);

  const int rw = (blockIdx.x - 256)*64 + w*16;  // 1024 blocks x 64 rows
  short8 A0, A1;
  {
    const float4* ap0 = (const float4*)(data + (size_t)(rw + m)*64 + quad*8);
    float4 q0 = ap0[0], q1 = ap0[1];
    A0[0]=f2b(q0.x); A0[1]=f2b(q0.y); A0[2]=f2b(q0.z); A0[3]=f2b(q0.w);
    A0[4]=f2b(q1.x); A0[5]=f2b(q1.y); A0[6]=f2b(q1.z); A0[7]=f2b(q1.w);
    const float4* ap1 = (const float4*)(data + (size_t)(rw + m)*64 + 32 + quad*8);
    float4 q2 = ap1[0], q3 = ap1[1];
    A1[0]=f2b(q2.x); A1[1]=f2b(q2.y); A1[2]=f2b(q2.z); A1[3]=f2b(q2.w);
    A1[4]=f2b(q3.x); A1[5]=f2b(q3.y); A1[6]=f2b(q3.z); A1[7]=f2b(q3.w);
  }
  floatx4 acc[4];
  #pragma unroll
  for (int ct = 0; ct < 4; ++ct){
    floatx4 z = {0.f, 0.f, 0.f, 0.f};
    acc[ct] = __builtin_amdgcn_mfma_f32_16x16x32_bf16(A0, B[ct][0], z, 0, 0, 0);
    acc[ct] = __builtin_amdgcn_mfma_f32_16x16x32_bf16(A1, B[ct][1], acc[ct], 0, 0, 0);
  }
  float p1[4] = {0.f,0.f,0.f,0.f}, p2[4] = {0.f,0.f,0.f,0.f};
  #pragma unroll
  for (int ct = 0; ct < 4; ++ct){
    const float wi = att_i[ct*16 + m], wj = att_j[ct*16 + m];
    #pragma unroll
    for (int reg = 0; reg < 4; ++reg){
      float v = acc[ct][reg];
      const int row = rw + quad*4 + reg;
      xl[(size_t)row*64 + ct*16 + m] = __float2bfloat16(v);
      p1[reg] = fmaf(v, wi, p1[reg]);
      p2[reg] = fmaf(v, wj, p2[reg]);
    }
  }
  #pragma unroll
  for (int reg = 0; reg < 4; ++reg){
    #pragma unroll
    for (int s = 1; s < 16; s <<= 1){
      p1[reg] += __shfl_xor(p1[reg], s, 16);
      p2[reg] += __shfl_xor(p2[reg], s, 16);
    }
    if (m == 0){
      const int r = rw + quad*4 + reg;
      aip[r] = p1[reg];                      // emi/emj added in k_attn_agg
      ajp[r] = p2[reg];
    }
  }
  LAG_TAIL(ctr);
}

// ---------------- K2 v3: softmax phase -> LDS alpha; aggregation with 16 lanes/node,
// ushort4 (8B) row-slices. 1 addr calc per 4 elements, zero shuffles in inner loop. ----------------
__global__ void __launch_bounds__(256) k_attn_agg(const int* __restrict__ topk,
                         const __hip_bfloat16* __restrict__ xl,
                         fpc aip, fpc ajp, fpc emi_g, fpc emj_g, fpc gnn_bias,
                         __hip_bfloat16* __restrict__ agg, float* __restrict__ bnsum){
  __shared__ int    s_topk[32*TK];          // 2.5 KB
  __shared__ float  s_alpha[32][21];        // 2.7 KB
  __shared__ float  s_ai[32];               // aip[v] + emi[i]
  __shared__ float  s_aj[256];              // ajp[b*256+k] + emj[k]
  __shared__ float4 s_ps[16][16], s_pq[16][16];   // 8 KB
  const int t = threadIdx.x, w = t >> 6, lane = t & 63;
  const int b  = blockIdx.x >> 3;           // batch (8 blocks per batch)
  const int i0 = (blockIdx.x & 7) * 32;     // first node id within batch

  // ----- staging (coalesced, tiny) -----
  for (int x = t; x < 32*TK; x += 256) s_topk[x] = topk[i0*TK + x];
  s_aj[t] = ajp[b*256 + t] + emj_g[t];
  if (t < 32) s_ai[t] = aip[blockIdx.x*32 + t] + emi_g[i0 + t];
  __syncthreads();

  // ----- phase 1: dual-half softmax, 8 nodes/wave, alpha -> LDS -----
  const int k32 = lane & 31, half = lane >> 5;
  #pragma unroll
  for (int j = 0; j < 4; ++j){
    const int nloc = w*8 + j*2 + half;
    const int i = i0 + nloc;
    float lg = -1e30f;
    if (k32 < 21){
      int sl = (k32 < 20) ? s_topk[nloc*TK + k32] : i;
      if (k32 == 20 || sl != i){            // remove_self_loops, keep appended loop
        float l = s_ai[nloc] + s_aj[sl];
        lg = (l >= 0.f) ? l : 0.2f*l;       // leaky_relu(0.2)
      }
    }
    float m = lg;
    for (int s = 1; s < 32; s <<= 1) m = fmaxf(m, __shfl_xor(m, s, 32));
    float e = (lg > -1e29f) ? __expf(lg - m) : 0.f;
    float den = e;
    for (int s = 1; s < 32; s <<= 1) den += __shfl_xor(den, s, 32);
    if (k32 < 21) s_alpha[nloc][k32] = e / den;   // alpha==0 for masked self-dup edges
  }
  __syncthreads();

  // ----- phase 2: aggregation, 4 nodes in parallel per wave (16 lanes/node) -----
  const int g = lane >> 4, m4 = lane & 15;  // group=node slot, m4=dim quad
  const float4 bias4 = *(const float4*)(gnn_bias + m4*4);
  const unsigned short* xb = (const unsigned short*)(xl + (size_t)b*16384);
  float4 ps = {0.f,0.f,0.f,0.f}, pq = {0.f,0.f,0.f,0.f};
  #pragma unroll
  for (int jj = 0; jj < 2; ++jj){
    const int n = w*8 + jj*4 + g;
    float4 acc = bias4;
    #pragma unroll
    for (int k = 0; k < 21; ++k){
      const int r = (k < 20) ? s_topk[n*TK + k] : (i0 + n);  // uniform per group
      const float a = s_alpha[n][k];                          // uniform per group
      ushort4 u = *(const ushort4*)(xb + r*64 + m4*4);        // 8B of gathered row
      acc.x = fmaf(a, b2fu(u.x), acc.x);
      acc.y = fmaf(a, b2fu(u.y), acc.y);
      acc.z = fmaf(a, b2fu(u.z), acc.z);
      acc.w = fmaf(a, b2fu(u.w), acc.w);
    }
    const size_t v = (size_t)blockIdx.x*32 + n;
    ushort4 o;
    o.x = (unsigned short)f2b(acc.x); o.y = (unsigned short)f2b(acc.y);
    o.z = (unsigned short)f2b(acc.z); o.w = (unsigned short)f2b(acc.w);
    *(ushort4*)((unsigned short*)agg + v*64 + m4*4) = o;
    ps.x += acc.x; ps.y += acc.y; ps.z += acc.z; ps.w += acc.w;
    pq.x = fmaf(acc.x, acc.x, pq.x); pq.y = fmaf(acc.y, acc.y, pq.y);
    pq.z = fmaf(acc.z, acc.z, pq.z); pq.w = fmaf(acc.w, acc.w, pq.w);
  }
  s_ps[w*4 + g][m4] = ps; s_pq[w*4 + g][m4] = pq;
  __syncthreads();
  if (t < 64){
    const int mm = t >> 2, c = t & 3;
    float S = 0.f, Q = 0.f;
    #pragma unroll
    for (int r = 0; r < 16; ++r){
      S += ((const float*)&s_ps[r][mm])[c];
      Q += ((const float*)&s_pq[r][mm])[c];
    }
    const int cp = (blockIdx.x & 7)*64;
    atomicAdd(&bnsum[cp + t], S);
    atomicAdd(&bnsum[512 + cp + t], Q);
  }
}

// ---------------- K3: block-range split -- enc MFMA (blocks 0..255) | bn2 stats (256..2303) ----------------
// part now written TRANSPOSED: part[row][kt][dim] so K4-redarr reads contiguous.
__global__ void __launch_bounds__(256) k_encst(const __hip_bfloat16* __restrict__ agg, fpc enc_w,
                         fpc emb, fpc g1, fpc be1,
                         float* __restrict__ bnsum, float* __restrict__ part,
                         int* __restrict__ ctr){
  const int t = threadIdx.x;

  if (blockIdx.x < 256){
    // ===== enc path: kt in [0,128), bt in [0,2) =====
    const int w = t >> 6, lane = t & 63;
    const int m = lane & 15, quad = lane >> 4;
    const int kt = blockIdx.x & 127, bt = blockIdx.x >> 7, kbase = kt*128;
    float scA[8], shA[8], scB[8], shB[8];
    #pragma unroll
    for (int j = 0; j < 8; ++j){
      #pragma unroll
      for (int par = 0; par < 2; ++par){
        const int d = par*32 + quad*8 + j;
        float S = 0.f, Q = 0.f;
        #pragma unroll
        for (int cp = 0; cp < 8; ++cp){ S += bnsum[cp*64 + d]; Q += bnsum[512 + cp*64 + d]; }
        float mean = S * (1.f/BN);
        float var  = Q * (1.f/BN) - mean*mean;
        float sc = g1[d] * rsqrtf(var + 1e-5f);
        float sh = be1[d] - mean*sc;
        if (par == 0){ scA[j] = sc; shA[j] = sh; } else { scB[j] = sc; shB[j] = sh; }
      }
    }
    floatx4 acc[2][4];
    #pragma unroll
    for (int i = 0; i < 2; ++i)
      #pragma unroll
      for (int ct = 0; ct < 4; ++ct)
        acc[i][ct] = (floatx4){0.f, 0.f, 0.f, 0.f};

    #pragma unroll
    for (int kc = 0; kc < 4; ++kc){
      const int kof = kbase + kc*32 + quad*8;
      const bool odd = (kc & 1);
      short8 Bf[4];
      #pragma unroll
      for (int ct = 0; ct < 4; ++ct)
        #pragma unroll
        for (int j = 0; j < 8; ++j)
          Bf[ct][j] = f2b(enc_w[(size_t)(kof + j)*64 + ct*16 + m]);
      #pragma unroll
      for (int i = 0; i < 2; ++i){
        const int row = bt*128 + (w*2 + i)*16 + m;
        uint4 uu = *(const uint4*)((const unsigned short*)agg + (size_t)row*16384 + kof);
        unsigned short h[8] = {
          (unsigned short)(uu.x & 0xffff), (unsigned short)(uu.x >> 16),
          (unsigned short)(uu.y & 0xffff), (unsigned short)(uu.y >> 16),
          (unsigned short)(uu.z & 0xffff), (unsigned short)(uu.z >> 16),
          (unsigned short)(uu.w & 0xffff), (unsigned short)(uu.w >> 16) };
        short8 Af;
        if (!odd){
          #pragma unroll
          for (int j = 0; j < 8; ++j) Af[j] = f2b(fmaxf(fmaf(b2fu(h[j]), scA[j], shA[j]), 0.f));
        } else {
          #pragma unroll
          for (int j = 0; j < 8; ++j) Af[j] = f2b(fmaxf(fmaf(b2fu(h[j]), scB[j], shB[j]), 0.f));
        }
        #pragma unroll
        for (int ct = 0; ct < 4; ++ct)
          acc[i][ct] = __builtin_amdgcn_mfma_f32_16x16x32_bf16(Af, Bf[ct], acc[i][ct], 0, 0, 0);
      }
    }
    #pragma unroll
    for (int i = 0; i < 2; ++i)
      #pragma unroll
      for (int ct = 0; ct < 4; ++ct)
        #pragma unroll
        for (int reg = 0; reg < 4; ++reg){
          const int row = bt*128 + (w*2 + i)*16 + quad*4 + reg;
          part[(size_t)row*8192 + kt*64 + ct*16 + m] = acc[i][ct][reg];  // [row][kt][dim]
        }
    LAG_TAIL(ctr);
    return;
  }

  // ===== stats path: bn2 stats over bf16 agg (2048 blocks x 32 rows) =====
  const int sb = blockIdx.x - 256;
  const int qc = t & 15, rs = t >> 4;
  float4 sc, sh;
  {
    float s[4], q[4];
    #pragma unroll
    for (int k = 0; k < 4; ++k){
      const int d = qc*4 + k;
      float S = 0.f, Q = 0.f;
      #pragma unroll
      for (int cp = 0; cp < 8; ++cp){ S += bnsum[cp*64 + d]; Q += bnsum[512 + cp*64 + d]; }
      float mean = S * (1.f/BN);
      float var  = Q * (1.f/BN) - mean*mean;
      s[k] = g1[d] * rsqrtf(var + 1e-5f);
      q[k] = be1[d] - mean*s[k];
    }
    sc = make_float4(s[0], s[1], s[2], s[3]);
    sh = make_float4(q[0], q[1], q[2], q[3]);
  }
  const float4* emb4 = (const float4*)emb;
  float4 ys = make_float4(0,0,0,0), yq = make_float4(0,0,0,0);
  const int rbase = sb*32;
  #pragma unroll
  for (int jj = 0; jj < 2; ++jj){
    const int r = rbase + jj*16 + rs;
    ushort4 u = *(const ushort4*)((const unsigned short*)agg + (size_t)r*64 + qc*4);
    float4 e = emb4[(r & 255)*16 + qc];
    float4 y;
    y.x = fmaxf(fmaf(b2fu(u.x), sc.x, sh.x), 0.f) * e.x;
    y.y = fmaxf(fmaf(b2fu(u.y), sc.y, sh.y), 0.f) * e.y;
    y.z = fmaxf(fmaf(b2fu(u.z), sc.z, sh.z), 0.f) * e.z;
    y.w = fmaxf(fmaf(b2fu(u.w), sc.w, sh.w), 0.f) * e.w;
    ys.x += y.x; ys.y += y.y; ys.z += y.z; ys.w += y.w;
    yq.x = fmaf(y.x, y.x, yq.x); yq.y = fmaf(y.y, y.y, yq.y);
    yq.z = fmaf(y.z, y.z, yq.z); yq.w = fmaf(y.w, y.w, yq.w);
  }
  __shared__ float4 s_s[16][16], s_q[16][16];
  s_s[rs][qc] = ys; s_q[rs][qc] = yq;
  __syncthreads();
  if (t < 64){
    const int qq = t >> 2, comp = t & 3;
    float S = 0.f, Q = 0.f;
    #pragma unroll
    for (int rr = 0; rr < 16; ++rr){
      S += ((const float*)&s_s[rr][qq])[comp];
      Q += ((const float*)&s_q[rr][qq])[comp];
    }
    const int cp = (sb & 7)*64;
    atomicAdd(&bnsum[1024 + cp + t], S);
    atomicAdd(&bnsum[1536 + cp + t], Q);
  }
  LAG_TAIL(ctr);
}

// ---------------- K4: block-range split -- redarr (blocks 0..255) | score (256..2303) ----------------
__global__ void __launch_bounds__(256) k_fin(const float* __restrict__ part,
                      const __hip_bfloat16* __restrict__ agg, fpc emb,
                      fpc g1, fpc be1, fpc g2, fpc be2,
                      const float* __restrict__ bnsum,
                      fpc enc_b, fpc arr_w, fpc arr_b, fpc out_w, fpc out_b,
                      float* __restrict__ out, int* __restrict__ ctr){
  const int t = threadIdx.x;

  if (blockIdx.x < 256){
    // ===== redarr path: reduce split-K partials (contiguous [row][kt][dim]) + arrangement =====
    __shared__ float4 s_enc4[16][16];
    const int b = blockIdx.x;
    const int d4 = t & 15, kg = t >> 4;     // dim-quad, k-group (16 groups x 8 kt)
    float4 s = {0.f,0.f,0.f,0.f};
    #pragma unroll
    for (int j = 0; j < 8; ++j){
      float4 v = *(const float4*)(part + (size_t)b*8192 + (kg + 16*j)*64 + d4*4);
      s.x += v.x; s.y += v.y; s.z += v.z; s.w += v.w;
    }
    s_enc4[kg][d4] = s;
    __syncthreads();
    if (t < 64){
      const int mm = t >> 2, c = t & 3;
      float e = enc_b[t];
      #pragma unroll
      for (int r = 0; r < 16; ++r) e += ((const float*)&s_enc4[r][mm])[c];
      float o[7];
      #pragma unroll
      for (int j = 0; j < 7; ++j) o[j] = e * arr_w[t*7 + j];
      #pragma unroll
      for (int j = 0; j < 7; ++j)
        #pragma unroll
        for (int m = 1; m < 64; m <<= 1) o[j] += __shfl_xor(o[j], m, 64);
      if (t == 0){
        #pragma unroll
        for (int j = 0; j < 7; ++j) out[65536 + b*7 + j] = o[j] + arr_b[j];
      }
    }
    LAG_TAIL(ctr);
    return;
  }

  // ===== score path =====
  const int w = t >> 6, lane = t & 63;
  const int qc = lane & 15, rq = lane >> 4;
  float sc1[4], sh1[4], sc2[4], sh2[4], ow[4];
  #pragma unroll
  for (int k = 0; k < 4; ++k){
    const int d = qc*4 + k;
    float S1 = 0.f, Q1 = 0.f, S2 = 0.f, Q2 = 0.f;
    #pragma unroll
    for (int cp = 0; cp < 8; ++cp){
      S1 += bnsum[cp*64 + d];        Q1 += bnsum[512 + cp*64 + d];
      S2 += bnsum[1024 + cp*64 + d]; Q2 += bnsum[1536 + cp*64 + d];
    }
    float m1 = S1 * (1.f/BN), v1 = Q1 * (1.f/BN) - m1*m1;
    sc1[k] = g1[d] * rsqrtf(v1 + 1e-5f);
    sh1[k] = be1[d] - m1*sc1[k];
    float m2 = S2 * (1.f/BN), v2 = Q2 * (1.f/BN) - m2*m2;
    sc2[k] = g2[d] * rsqrtf(v2 + 1e-5f);
    sh2[k] = be2[d] - m2*sc2[k];
    ow[k]  = out_w[d];
  }
  const float ob = out_b[0];
  const float4* emb4 = (const float4*)emb;
  const int base = (blockIdx.x - 256)*32 + w*8;
  #pragma unroll
  for (int it = 0; it < 2; ++it){
    const int r = base + it*4 + rq;
    ushort4 u = *(const ushort4*)((const unsigned short*)agg + (size_t)r*64 + qc*4);
    float4 e4 = emb4[(r & 255)*16 + qc];
    float p = 0.f, g, y, yh;
    g = fmaxf(fmaf(b2fu(u.x), sc1[0], sh1[0]), 0.f); y = g*e4.x;
    yh = fmaxf(fmaf(y, sc2[0], sh2[0]), 0.f); p = fmaf(yh, ow[0], p);
    g = fmaxf(fmaf(b2fu(u.y), sc1[1], sh1[1]), 0.f); y = g*e4.y;
    yh = fmaxf(fmaf(y, sc2[1], sh2[1]), 0.f); p = fmaf(yh, ow[1], p);
    g = fmaxf(fmaf(b2fu(u.z), sc1[2], sh1[2]), 0.f); y = g*e4.z;
    yh = fmaxf(fmaf(y, sc2[2], sh2[2]), 0.f); p = fmaf(yh, ow[2], p);
    g = fmaxf(fmaf(b2fu(u.w), sc1[3], sh1[3]), 0.f); y = g*e4.w;
    yh = fmaxf(fmaf(y, sc2[3], sh2[3]), 0.f); p = fmaf(yh, ow[3], p);
    #pragma unroll
    for (int mm = 1; mm < 16; mm <<= 1) p += __shfl_xor(p, mm, 16);
    if (qc == 0) out[r] = p + ob;
  }
  LAG_TAIL(ctr);
}

extern "C" void kernel_launch(void* const* d_in, const int* in_sizes, int n_in,
                              void* d_out, int out_size, void* d_ws, size_t ws_size,
                              hipStream_t stream) {
  fpc data     = (fpc)d_in[0];
  fpc emb      = (fpc)d_in[1];
  fpc lin_w    = (fpc)d_in[2];
  fpc att_i    = (fpc)d_in[3];
  fpc att_j    = (fpc)d_in[4];
  fpc att_em_i = (fpc)d_in[5];
  fpc att_em_j = (fpc)d_in[6];
  fpc gnn_bias = (fpc)d_in[7];
  fpc g1       = (fpc)d_in[8];
  fpc be1      = (fpc)d_in[9];
  fpc g2       = (fpc)d_in[10];
  fpc be2      = (fpc)d_in[11];
  fpc enc_w    = (fpc)d_in[12];
  fpc enc_b    = (fpc)d_in[13];
  fpc arr_w    = (fpc)d_in[14];
  fpc arr_b    = (fpc)d_in[15];
  fpc out_w    = (fpc)d_in[16];
  fpc out_b    = (fpc)d_in[17];

  float* fw = (float*)d_ws;
  int*   topk    = (int*)d_ws;            // [0, 5120)
  float* emi     = fw + 5120;             // 256
  float* emj     = fw + 5376;             // 256
  float* bnsum   = fw + 5632;             // 2048 shadow BN accumulators (zeroed by k_gx block 0)
  float* aip     = fw + 7680;             // 65536
  float* ajp     = fw + 73216;            // 65536
  __hip_bfloat16* agg = (__hip_bfloat16*)(fw + 138752);  // 65536*64 bf16 = 8.39 MB
  __hip_bfloat16* xl  = (__hip_bfloat16*)(fw + 2235904); // 65536*64 bf16 = 8.39 MB
  float* part    = (float*)xl;            // 256*128*64 f32 [row][kt][dim] = 8.39 MB, aliases dead xl
  int*   ctr     = (int*)(fw + 5000000);  // lag counters, well past live data
  float* out     = (float*)d_out;

  hipMemsetAsync(ctr, 0, 4*sizeof(int), stream);

  k_gx       <<<1280,  256, 0, stream>>>(data, emb, lin_w, att_i, att_j, att_em_i, att_em_j,
                                         topk, emi, emj, xl, aip, ajp, bnsum, ctr+0);
  k_attn_agg <<<2048,  256, 0, stream>>>(topk, xl, aip, ajp, emi, emj, gnn_bias, agg, bnsum);
  k_encst    <<<2304,  256, 0, stream>>>(agg, enc_w, emb, g1, be1, bnsum, part, ctr+2);
  k_fin      <<<2304,  256, 0, stream>>>(part, agg, emb, g1, be1, g2, be2, bnsum,
                                         enc_b, arr_w, arr_b, out_w, out_b, out, ctr+3);
}

// Round 6
// 223.141 us; speedup vs baseline: 1.8892x; 1.5949x over previous
//
#include <hip/hip_runtime.h>
#include <hip/hip_bf16.h>

#define TK 20
#define BN 65536

typedef const float* fpc;
typedef __attribute__((ext_vector_type(8))) short short8;
typedef __attribute__((ext_vector_type(4))) float floatx4;

// f32 -> bf16 bits, round-to-nearest-even
__device__ __forceinline__ short f2b(float f){
  unsigned u = __float_as_uint(f);
  return (short)((u + 0x7fffu + ((u >> 16) & 1u)) >> 16);
}
__device__ __forceinline__ float b2fu(unsigned short u){
  return __uint_as_float(((unsigned)u) << 16);
}

// --- instrumentation (K2 only this round): last-finishing block spins so the
// kernel rises above harness poison-fills in top-5 with full counters.
// shown = true + S, S ~= 120k cyc / 1.95GHz ~= 61.6us (round-3 calibration).
__device__ __forceinline__ void lag_spin(unsigned long long cyc){
  unsigned long long t0 = __builtin_readcyclecounter();
  while (__builtin_readcyclecounter() - t0 < cyc) { }
}
#define LAG_TAIL(CTR) do{ \
    if (threadIdx.x == 0){ \
      int _v = atomicAdd((CTR), 1); \
      if (_v == (int)gridDim.x - 1) lag_spin(120000ULL); \
    } }while(0)

// ---------------- K1: graph (0..255, block 0 zeroes bnsum) | xl MFMA (256..1279) | enc_w transpose (1280..1535) ----------------
__global__ void __launch_bounds__(256) k_gx(fpc data, fpc emb, fpc lin_w, fpc att_i, fpc att_j,
        fpc att_em_i, fpc att_em_j, fpc enc_w,
        int* __restrict__ topk, float* __restrict__ emi, float* __restrict__ emj,
        __hip_bfloat16* __restrict__ xl, float* __restrict__ aip, float* __restrict__ ajp,
        float* __restrict__ bnsum, unsigned short* __restrict__ enc_wt){
  __shared__ float s_cos[256];
  __shared__ float s_wi[64];
  __shared__ float s_t[64][65];
  const int t = threadIdx.x, w = t >> 6, lane = t & 63;

  if (blockIdx.x >= 1280){
    // ----- enc_w transpose: 64 K-rows/block -> bf16 tiled [K/8][64][8] -----
    const int kb = blockIdx.x - 1280;      // 256 blocks x 64 rows = 16384 K-rows
    #pragma unroll
    for (int p = 0; p < 16; ++p){
      const int row = p*4 + (t >> 6), col = t & 63;
      s_t[row][col] = enc_w[(size_t)(kb*64 + row)*64 + col];
    }
    __syncthreads();
    #pragma unroll
    for (int p = 0; p < 2; ++p){
      const int kq = p*4 + (t >> 6), c = t & 63;   // kq in [0,8): group of 8 K-rows
      short8 o;
      #pragma unroll
      for (int j = 0; j < 8; ++j) o[j] = f2b(s_t[kq*8 + j][c]);
      *(short8*)(enc_wt + ((size_t)kb*8 + kq)*512 + c*8) = o;
    }
    return;
  }

  if (blockIdx.x < 256){
    if (blockIdx.x == 0){
      #pragma unroll
      for (int i = 0; i < 8; ++i) bnsum[t + i*256] = 0.f;   // zero shadow BN accumulators
    }
    // ----- graph part: top-20 cosine + emi/emj -----
    const int i = blockIdx.x;
    if (t < 64) s_wi[t] = emb[i*64 + t];
    __syncthreads();
    float dot = 0.f, nj = 0.f, ni = 0.f;
    for (int f = 0; f < 64; ++f){
      float wj = emb[t*64 + f], wi = s_wi[f];
      dot = fmaf(wi, wj, dot); nj = fmaf(wj, wj, nj); ni = fmaf(wi, wi, ni);
    }
    s_cos[t] = dot / (sqrtf(ni) * sqrtf(nj));
    __syncthreads();
    if (t < 64){
      float v0 = s_cos[t], v1 = s_cos[t+64], v2 = s_cos[t+128], v3 = s_cos[t+192];
      int taken = 0;
      for (int r = 0; r < TK; ++r){
        float bv = (taken & 1) ? -3.f : v0; int bi = t;
        float c;
        c = (taken & 2) ? -3.f : v1; if (c > bv){ bv = c; bi = t+64;  }
        c = (taken & 4) ? -3.f : v2; if (c > bv){ bv = c; bi = t+128; }
        c = (taken & 8) ? -3.f : v3; if (c > bv){ bv = c; bi = t+192; }
        for (int m = 1; m < 64; m <<= 1){
          float ov = __shfl_xor(bv, m, 64);
          int   oi = __shfl_xor(bi, m, 64);
          if (ov > bv || (ov == bv && oi < bi)){ bv = ov; bi = oi; }
        }
        if (t == 0) topk[i*TK + r] = bi;
        if ((bi & 63) == t) taken |= 1 << (bi >> 6);
      }
    } else if (t < 128){
      int d = t - 64;
      float wv = s_wi[d];
      float p1 = wv * att_em_i[d];
      float p2 = wv * att_em_j[d];
      for (int m = 1; m < 64; m <<= 1){
        p1 += __shfl_xor(p1, m, 64);
        p2 += __shfl_xor(p2, m, 64);
      }
      if (d == 0){ emi[i] = p1; emj[i] = p2; }
    }
    return;
  }

  // ----- xl part: data @ lin_w via MFMA 16x16x32 bf16 -----
  const int m = lane & 15, quad = lane >> 4;
  short8 B[4][2];
  #pragma unroll
  for (int ct = 0; ct < 4; ++ct)
    #pragma unroll
    for (int kc = 0; kc < 2; ++kc)
      #pragma unroll
      for (int j = 0; j < 8; ++j)
        B[ct][kc][j] = f2b(lin_w[(kc*32 + quad*8 + j)*64 + ct*16 + m]);

  const int rw = (blockIdx.x - 256)*64 + w*16;  // 1024 blocks x 64 rows
  short8 A0, A1;
  {
    const float4* ap0 = (const float4*)(data + (size_t)(rw + m)*64 + quad*8);
    float4 q0 = ap0[0], q1 = ap0[1];
    A0[0]=f2b(q0.x); A0[1]=f2b(q0.y); A0[2]=f2b(q0.z); A0[3]=f2b(q0.w);
    A0[4]=f2b(q1.x); A0[5]=f2b(q1.y); A0[6]=f2b(q1.z); A0[7]=f2b(q1.w);
    const float4* ap1 = (const float4*)(data + (size_t)(rw + m)*64 + 32 + quad*8);
    float4 q2 = ap1[0], q3 = ap1[1];
    A1[0]=f2b(q2.x); A1[1]=f2b(q2.y); A1[2]=f2b(q2.z); A1[3]=f2b(q2.w);
    A1[4]=f2b(q3.x); A1[5]=f2b(q3.y); A1[6]=f2b(q3.z); A1[7]=f2b(q3.w);
  }
  floatx4 acc[4];
  #pragma unroll
  for (int ct = 0; ct < 4; ++ct){
    floatx4 z = {0.f, 0.f, 0.f, 0.f};
    acc[ct] = __builtin_amdgcn_mfma_f32_16x16x32_bf16(A0, B[ct][0], z, 0, 0, 0);
    acc[ct] = __builtin_amdgcn_mfma_f32_16x16x32_bf16(A1, B[ct][1], acc[ct], 0, 0, 0);
  }
  float p1[4] = {0.f,0.f,0.f,0.f}, p2[4] = {0.f,0.f,0.f,0.f};
  #pragma unroll
  for (int ct = 0; ct < 4; ++ct){
    const float wi = att_i[ct*16 + m], wj = att_j[ct*16 + m];
    #pragma unroll
    for (int reg = 0; reg < 4; ++reg){
      float v = acc[ct][reg];
      const int row = rw + quad*4 + reg;
      xl[(size_t)row*64 + ct*16 + m] = __float2bfloat16(v);
      p1[reg] = fmaf(v, wi, p1[reg]);
      p2[reg] = fmaf(v, wj, p2[reg]);
    }
  }
  #pragma unroll
  for (int reg = 0; reg < 4; ++reg){
    #pragma unroll
    for (int s = 1; s < 16; s <<= 1){
      p1[reg] += __shfl_xor(p1[reg], s, 16);
      p2[reg] += __shfl_xor(p2[reg], s, 16);
    }
    if (m == 0){
      const int r = rw + quad*4 + reg;
      aip[r] = p1[reg];                      // emi/emj added in k_attn_agg
      ajp[r] = p2[reg];
    }
  }
}

// ---------------- K2 v3 (+spin): softmax -> LDS alpha; aggregation 16 lanes/node, ushort4 slices ----------------
__global__ void __launch_bounds__(256) k_attn_agg(const int* __restrict__ topk,
                         const __hip_bfloat16* __restrict__ xl,
                         fpc aip, fpc ajp, fpc emi_g, fpc emj_g, fpc gnn_bias,
                         __hip_bfloat16* __restrict__ agg, float* __restrict__ bnsum,
                         int* __restrict__ ctr){
  __shared__ int    s_topk[32*TK];          // 2.5 KB
  __shared__ float  s_alpha[32][21];        // 2.7 KB
  __shared__ float  s_ai[32];               // aip[v] + emi[i]
  __shared__ float  s_aj[256];              // ajp[b*256+k] + emj[k]
  __shared__ float4 s_ps[16][16], s_pq[16][16];   // 8 KB
  const int t = threadIdx.x, w = t >> 6, lane = t & 63;
  const int b  = blockIdx.x >> 3;           // batch (8 blocks per batch)
  const int i0 = (blockIdx.x & 7) * 32;     // first node id within batch

  // ----- staging (coalesced, tiny) -----
  for (int x = t; x < 32*TK; x += 256) s_topk[x] = topk[i0*TK + x];
  s_aj[t] = ajp[b*256 + t] + emj_g[t];
  if (t < 32) s_ai[t] = aip[blockIdx.x*32 + t] + emi_g[i0 + t];
  __syncthreads();

  // ----- phase 1: dual-half softmax, 8 nodes/wave, alpha -> LDS -----
  const int k32 = lane & 31, half = lane >> 5;
  #pragma unroll
  for (int j = 0; j < 4; ++j){
    const int nloc = w*8 + j*2 + half;
    const int i = i0 + nloc;
    float lg = -1e30f;
    if (k32 < 21){
      int sl = (k32 < 20) ? s_topk[nloc*TK + k32] : i;
      if (k32 == 20 || sl != i){            // remove_self_loops, keep appended loop
        float l = s_ai[nloc] + s_aj[sl];
        lg = (l >= 0.f) ? l : 0.2f*l;       // leaky_relu(0.2)
      }
    }
    float m = lg;
    for (int s = 1; s < 32; s <<= 1) m = fmaxf(m, __shfl_xor(m, s, 32));
    float e = (lg > -1e29f) ? __expf(lg - m) : 0.f;
    float den = e;
    for (int s = 1; s < 32; s <<= 1) den += __shfl_xor(den, s, 32);
    if (k32 < 21) s_alpha[nloc][k32] = e / den;   // alpha==0 for masked self-dup edges
  }
  __syncthreads();

  // ----- phase 2: aggregation, 4 nodes in parallel per wave (16 lanes/node) -----
  const int g = lane >> 4, m4 = lane & 15;  // group=node slot, m4=dim quad
  const float4 bias4 = *(const float4*)(gnn_bias + m4*4);
  const unsigned short* xb = (const unsigned short*)(xl + (size_t)b*16384);
  float4 ps = {0.f,0.f,0.f,0.f}, pq = {0.f,0.f,0.f,0.f};
  #pragma unroll
  for (int jj = 0; jj < 2; ++jj){
    const int n = w*8 + jj*4 + g;
    float4 acc = bias4;
    #pragma unroll
    for (int k = 0; k < 21; ++k){
      const int r = (k < 20) ? s_topk[n*TK + k] : (i0 + n);  // uniform per group
      const float a = s_alpha[n][k];                          // uniform per group
      ushort4 u = *(const ushort4*)(xb + r*64 + m4*4);        // 8B of gathered row
      acc.x = fmaf(a, b2fu(u.x), acc.x);
      acc.y = fmaf(a, b2fu(u.y), acc.y);
      acc.z = fmaf(a, b2fu(u.z), acc.z);
      acc.w = fmaf(a, b2fu(u.w), acc.w);
    }
    const size_t v = (size_t)blockIdx.x*32 + n;
    ushort4 o;
    o.x = (unsigned short)f2b(acc.x); o.y = (unsigned short)f2b(acc.y);
    o.z = (unsigned short)f2b(acc.z); o.w = (unsigned short)f2b(acc.w);
    *(ushort4*)((unsigned short*)agg + v*64 + m4*4) = o;
    ps.x += acc.x; ps.y += acc.y; ps.z += acc.z; ps.w += acc.w;
    pq.x = fmaf(acc.x, acc.x, pq.x); pq.y = fmaf(acc.y, acc.y, pq.y);
    pq.z = fmaf(acc.z, acc.z, pq.z); pq.w = fmaf(acc.w, acc.w, pq.w);
  }
  s_ps[w*4 + g][m4] = ps; s_pq[w*4 + g][m4] = pq;
  __syncthreads();
  if (t < 64){
    const int mm = t >> 2, c = t & 3;
    float S = 0.f, Q = 0.f;
    #pragma unroll
    for (int r = 0; r < 16; ++r){
      S += ((const float*)&s_ps[r][mm])[c];
      Q += ((const float*)&s_pq[r][mm])[c];
    }
    const int cp = (blockIdx.x & 7)*64;
    atomicAdd(&bnsum[cp + t], S);
    atomicAdd(&bnsum[512 + cp + t], Q);
  }
  LAG_TAIL(ctr);
}

// ---------------- K3: enc MFMA w/ pre-transposed B (0..255) | bn2 stats (256..2303) ----------------
__global__ void __launch_bounds__(256) k_encst(const __hip_bfloat16* __restrict__ agg,
                         const unsigned short* __restrict__ enc_wt,
                         fpc emb, fpc g1, fpc be1,
                         float* __restrict__ bnsum, float* __restrict__ part){
  const int t = threadIdx.x;
  __shared__ float s_sc[64], s_sh[64];

  // bn1 scale/shift once per block (64 threads, 16 loads each) -- bit-identical math
  if (t < 64){
    float S = 0.f, Q = 0.f;
    #pragma unroll
    for (int cp = 0; cp < 8; ++cp){ S += bnsum[cp*64 + t]; Q += bnsum[512 + cp*64 + t]; }
    float mean = S * (1.f/BN);
    float var  = Q * (1.f/BN) - mean*mean;
    float sc = g1[t] * rsqrtf(var + 1e-5f);
    s_sc[t] = sc;
    s_sh[t] = be1[t] - mean*sc;
  }
  __syncthreads();

  if (blockIdx.x < 256){
    // ===== enc path: kt in [0,128), bt in [0,2) =====
    const int w = t >> 6, lane = t & 63;
    const int m = lane & 15, quad = lane >> 4;
    const int kt = blockIdx.x & 127, bt = blockIdx.x >> 7, kbase = kt*128;
    float scA[8], shA[8], scB[8], shB[8];
    #pragma unroll
    for (int j = 0; j < 8; ++j){
      scA[j] = s_sc[quad*8 + j];      shA[j] = s_sh[quad*8 + j];
      scB[j] = s_sc[32 + quad*8 + j]; shB[j] = s_sh[32 + quad*8 + j];
    }
    floatx4 acc[2][4];
    #pragma unroll
    for (int i = 0; i < 2; ++i)
      #pragma unroll
      for (int ct = 0; ct < 4; ++ct)
        acc[i][ct] = (floatx4){0.f, 0.f, 0.f, 0.f};

    #pragma unroll
    for (int kc = 0; kc < 4; ++kc){
      const int kof = kbase + kc*32 + quad*8;
      const bool odd = (kc & 1);
      const unsigned short* bp = enc_wt + (size_t)(kof >> 3)*512 + m*8;
      short8 Bf[4];
      #pragma unroll
      for (int ct = 0; ct < 4; ++ct)
        Bf[ct] = *(const short8*)(bp + ct*128);   // fully coalesced 16B/lane
      #pragma unroll
      for (int i = 0; i < 2; ++i){
        const int row = bt*128 + (w*2 + i)*16 + m;
        uint4 uu = *(const uint4*)((const unsigned short*)agg + (size_t)row*16384 + kof);
        unsigned short h[8] = {
          (unsigned short)(uu.x & 0xffff), (unsigned short)(uu.x >> 16),
          (unsigned short)(uu.y & 0xffff), (unsigned short)(uu.y >> 16),
          (unsigned short)(uu.z & 0xffff), (unsigned short)(uu.z >> 16),
          (unsigned short)(uu.w & 0xffff), (unsigned short)(uu.w >> 16) };
        short8 Af;
        if (!odd){
          #pragma unroll
          for (int j = 0; j < 8; ++j) Af[j] = f2b(fmaxf(fmaf(b2fu(h[j]), scA[j], shA[j]), 0.f));
        } else {
          #pragma unroll
          for (int j = 0; j < 8; ++j) Af[j] = f2b(fmaxf(fmaf(b2fu(h[j]), scB[j], shB[j]), 0.f));
        }
        #pragma unroll
        for (int ct = 0; ct < 4; ++ct)
          acc[i][ct] = __builtin_amdgcn_mfma_f32_16x16x32_bf16(Af, Bf[ct], acc[i][ct], 0, 0, 0);
      }
    }
    #pragma unroll
    for (int i = 0; i < 2; ++i)
      #pragma unroll
      for (int ct = 0; ct < 4; ++ct)
        #pragma unroll
        for (int reg = 0; reg < 4; ++reg){
          const int row = bt*128 + (w*2 + i)*16 + quad*4 + reg;
          part[(size_t)row*8192 + kt*64 + ct*16 + m] = acc[i][ct][reg];  // [row][kt][dim]
        }
    return;
  }

  // ===== stats path: bn2 stats over bf16 agg (2048 blocks x 32 rows) =====
  const int sb = blockIdx.x - 256;
  const int qc = t & 15, rs = t >> 4;
  float4 sc, sh;
  sc = make_float4(s_sc[qc*4], s_sc[qc*4+1], s_sc[qc*4+2], s_sc[qc*4+3]);
  sh = make_float4(s_sh[qc*4], s_sh[qc*4+1], s_sh[qc*4+2], s_sh[qc*4+3]);
  const float4* emb4 = (const float4*)emb;
  float4 ys = make_float4(0,0,0,0), yq = make_float4(0,0,0,0);
  const int rbase = sb*32;
  #pragma unroll
  for (int jj = 0; jj < 2; ++jj){
    const int r = rbase + jj*16 + rs;
    ushort4 u = *(const ushort4*)((const unsigned short*)agg + (size_t)r*64 + qc*4);
    float4 e = emb4[(r & 255)*16 + qc];
    float4 y;
    y.x = fmaxf(fmaf(b2fu(u.x), sc.x, sh.x), 0.f) * e.x;
    y.y = fmaxf(fmaf(b2fu(u.y), sc.y, sh.y), 0.f) * e.y;
    y.z = fmaxf(fmaf(b2fu(u.z), sc.z, sh.z), 0.f) * e.z;
    y.w = fmaxf(fmaf(b2fu(u.w), sc.w, sh.w), 0.f) * e.w;
    ys.x += y.x; ys.y += y.y; ys.z += y.z; ys.w += y.w;
    yq.x = fmaf(y.x, y.x, yq.x); yq.y = fmaf(y.y, y.y, yq.y);
    yq.z = fmaf(y.z, y.z, yq.z); yq.w = fmaf(y.w, y.w, yq.w);
  }
  __shared__ float4 s_s[16][16], s_q[16][16];
  s_s[rs][qc] = ys; s_q[rs][qc] = yq;
  __syncthreads();
  if (t < 64){
    const int qq = t >> 2, comp = t & 3;
    float S = 0.f, Q = 0.f;
    #pragma unroll
    for (int rr = 0; rr < 16; ++rr){
      S += ((const float*)&s_s[rr][qq])[comp];
      Q += ((const float*)&s_q[rr][qq])[comp];
    }
    const int cp = (sb & 7)*64;
    atomicAdd(&bnsum[1024 + cp + t], S);
    atomicAdd(&bnsum[1536 + cp + t], Q);
  }
}

// ---------------- K4: redarr (0..255) | score (256..2303), bn params staged in LDS ----------------
__global__ void __launch_bounds__(256) k_fin(const float* __restrict__ part,
                      const __hip_bfloat16* __restrict__ agg, fpc emb,
                      fpc g1, fpc be1, fpc g2, fpc be2,
                      const float* __restrict__ bnsum,
                      fpc enc_b, fpc arr_w, fpc arr_b, fpc out_w, fpc out_b,
                      float* __restrict__ out){
  const int t = threadIdx.x;

  if (blockIdx.x < 256){
    // ===== redarr path: reduce split-K partials (contiguous [row][kt][dim]) + arrangement =====
    __shared__ float4 s_enc4[16][16];
    const int b = blockIdx.x;
    const int d4 = t & 15, kg = t >> 4;     // dim-quad, k-group (16 groups x 8 kt)
    float4 s = {0.f,0.f,0.f,0.f};
    #pragma unroll
    for (int j = 0; j < 8; ++j){
      float4 v = *(const float4*)(part + (size_t)b*8192 + (kg + 16*j)*64 + d4*4);
      s.x += v.x; s.y += v.y; s.z += v.z; s.w += v.w;
    }
    s_enc4[kg][d4] = s;
    __syncthreads();
    if (t < 64){
      const int mm = t >> 2, c = t & 3;
      float e = enc_b[t];
      #pragma unroll
      for (int r = 0; r < 16; ++r) e += ((const float*)&s_enc4[r][mm])[c];
      float o[7];
      #pragma unroll
      for (int j = 0; j < 7; ++j) o[j] = e * arr_w[t*7 + j];
      #pragma unroll
      for (int j = 0; j < 7; ++j)
        #pragma unroll
        for (int m = 1; m < 64; m <<= 1) o[j] += __shfl_xor(o[j], m, 64);
      if (t == 0){
        #pragma unroll
        for (int j = 0; j < 7; ++j) out[65536 + b*7 + j] = o[j] + arr_b[j];
      }
    }
    return;
  }

  // ===== score path: bn1/bn2 scale+shift computed once per block into LDS =====
  __shared__ float z1s[64], z1h[64], z2s[64], z2h[64], zow[64];
  if (t < 64){
    float S1 = 0.f, Q1 = 0.f, S2 = 0.f, Q2 = 0.f;
    #pragma unroll
    for (int cp = 0; cp < 8; ++cp){
      S1 += bnsum[cp*64 + t];        Q1 += bnsum[512 + cp*64 + t];
      S2 += bnsum[1024 + cp*64 + t]; Q2 += bnsum[1536 + cp*64 + t];
    }
    float m1 = S1 * (1.f/BN), v1 = Q1 * (1.f/BN) - m1*m1;
    float a1 = g1[t] * rsqrtf(v1 + 1e-5f);
    z1s[t] = a1; z1h[t] = be1[t] - m1*a1;
    float m2 = S2 * (1.f/BN), v2 = Q2 * (1.f/BN) - m2*m2;
    float a2 = g2[t] * rsqrtf(v2 + 1e-5f);
    z2s[t] = a2; z2h[t] = be2[t] - m2*a2;
    zow[t] = out_w[t];
  }
  __syncthreads();

  const int w = t >> 6, lane = t & 63;
  const int qc = lane & 15, rq = lane >> 4;
  float sc1[4], sh1[4], sc2[4], sh2[4], ow[4];
  #pragma unroll
  for (int k = 0; k < 4; ++k){
    const int d = qc*4 + k;
    sc1[k] = z1s[d]; sh1[k] = z1h[d];
    sc2[k] = z2s[d]; sh2[k] = z2h[d];
    ow[k]  = zow[d];
  }
  const float ob = out_b[0];
  const float4* emb4 = (const float4*)emb;
  const int base = (blockIdx.x - 256)*32 + w*8;
  #pragma unroll
  for (int it = 0; it < 2; ++it){
    const int r = base + it*4 + rq;
    ushort4 u = *(const ushort4*)((const unsigned short*)agg + (size_t)r*64 + qc*4);
    float4 e4 = emb4[(r & 255)*16 + qc];
    float p = 0.f, g, y, yh;
    g = fmaxf(fmaf(b2fu(u.x), sc1[0], sh1[0]), 0.f); y = g*e4.x;
    yh = fmaxf(fmaf(y, sc2[0], sh2[0]), 0.f); p = fmaf(yh, ow[0], p);
    g = fmaxf(fmaf(b2fu(u.y), sc1[1], sh1[1]), 0.f); y = g*e4.y;
    yh = fmaxf(fmaf(y, sc2[1], sh2[1]), 0.f); p = fmaf(yh, ow[1], p);
    g = fmaxf(fmaf(b2fu(u.z), sc1[2], sh1[2]), 0.f); y = g*e4.z;
    yh = fmaxf(fmaf(y, sc2[2], sh2[2]), 0.f); p = fmaf(yh, ow[2], p);
    g = fmaxf(fmaf(b2fu(u.w), sc1[3], sh1[3]), 0.f); y = g*e4.w;
    yh = fmaxf(fmaf(y, sc2[3], sh2[3]), 0.f); p = fmaf(yh, ow[3], p);
    #pragma unroll
    for (int mm = 1; mm < 16; mm <<= 1) p += __shfl_xor(p, mm, 16);
    if (qc == 0) out[r] = p + ob;
  }
}

extern "C" void kernel_launch(void* const* d_in, const int* in_sizes, int n_in,
                              void* d_out, int out_size, void* d_ws, size_t ws_size,
                              hipStream_t stream) {
  fpc data     = (fpc)d_in[0];
  fpc emb      = (fpc)d_in[1];
  fpc lin_w    = (fpc)d_in[2];
  fpc att_i    = (fpc)d_in[3];
  fpc att_j    = (fpc)d_in[4];
  fpc att_em_i = (fpc)d_in[5];
  fpc att_em_j = (fpc)d_in[6];
  fpc gnn_bias = (fpc)d_in[7];
  fpc g1       = (fpc)d_in[8];
  fpc be1      = (fpc)d_in[9];
  fpc g2       = (fpc)d_in[10];
  fpc be2      = (fpc)d_in[11];
  fpc enc_w    = (fpc)d_in[12];
  fpc enc_b    = (fpc)d_in[13];
  fpc arr_w    = (fpc)d_in[14];
  fpc arr_b    = (fpc)d_in[15];
  fpc out_w    = (fpc)d_in[16];
  fpc out_b    = (fpc)d_in[17];

  float* fw = (float*)d_ws;
  int*   topk    = (int*)d_ws;            // [0, 5120)
  float* emi     = fw + 5120;             // 256
  float* emj     = fw + 5376;             // 256
  float* bnsum   = fw + 5632;             // 2048 shadow BN accumulators (zeroed by k_gx block 0)
  float* aip     = fw + 7680;             // 65536
  float* ajp     = fw + 73216;            // 65536
  __hip_bfloat16* agg = (__hip_bfloat16*)(fw + 138752);  // 65536*64 bf16 = 8.39 MB
  __hip_bfloat16* xl  = (__hip_bfloat16*)(fw + 2235904); // 65536*64 bf16 = 8.39 MB
  float* part    = (float*)xl;            // 256*128*64 f32 [row][kt][dim] = 8.39 MB, aliases dead xl
  int*   ctr     = (int*)(fw + 5000000);  // lag counters, past live data
  unsigned short* enc_wt = (unsigned short*)(fw + 5242880); // 16384x64 bf16 tiled = 2 MB
  float* out     = (float*)d_out;

  hipMemsetAsync(ctr, 0, 4*sizeof(int), stream);

  k_gx       <<<1536,  256, 0, stream>>>(data, emb, lin_w, att_i, att_j, att_em_i, att_em_j,
                                         enc_w, topk, emi, emj, xl, aip, ajp, bnsum, enc_wt);
  k_attn_agg <<<2048,  256, 0, stream>>>(topk, xl, aip, ajp, emi, emj, gnn_bias, agg, bnsum, ctr+1);
  k_encst    <<<2304,  256, 0, stream>>>(agg, enc_wt, emb, g1, be1, bnsum, part);
  k_fin      <<<2304,  256, 0, stream>>>(part, agg, emb, g1, be1, g2, be2, bnsum,
                                         enc_b, arr_w, arr_b, out_w, out_b, out);
}

// Round 7
// 212.564 us; speedup vs baseline: 1.9832x; 1.0498x over previous
//
#include <hip/hip_runtime.h>
#include <hip/hip_bf16.h>

#define TK 20
#define BN 65536

typedef const float* fpc;
typedef __attribute__((ext_vector_type(8))) short short8;
typedef __attribute__((ext_vector_type(4))) float floatx4;

// f32 -> bf16 bits, round-to-nearest-even
__device__ __forceinline__ short f2b(float f){
  unsigned u = __float_as_uint(f);
  return (short)((u + 0x7fffu + ((u >> 16) & 1u)) >> 16);
}
__device__ __forceinline__ float b2fu(unsigned short u){
  return __uint_as_float(((unsigned)u) << 16);
}

// --- instrumentation (K2 only): last-finishing block spins so the kernel rises
// above harness poison-fills in top-5 with full counters.
// shown = true + S, S ~= 61.6us (round-3 calibration).
__device__ __forceinline__ void lag_spin(unsigned long long cyc){
  unsigned long long t0 = __builtin_readcyclecounter();
  while (__builtin_readcyclecounter() - t0 < cyc) { }
}
#define LAG_TAIL(CTR) do{ \
    if (threadIdx.x == 0){ \
      int _v = atomicAdd((CTR), 1); \
      if (_v == (int)gridDim.x - 1) lag_spin(120000ULL); \
    } }while(0)

// ---------------- K1: graph (0..255, block 0 zeroes bnsum) | xl MFMA (256..1279, XCD-aligned) | enc_w transpose (1280..1535) ----------------
__global__ void __launch_bounds__(256) k_gx(fpc data, fpc emb, fpc lin_w, fpc att_i, fpc att_j,
        fpc att_em_i, fpc att_em_j, fpc enc_w,
        int* __restrict__ topk, float* __restrict__ emi, float* __restrict__ emj,
        __hip_bfloat16* __restrict__ xl, float* __restrict__ aip, float* __restrict__ ajp,
        float* __restrict__ bnsum, unsigned short* __restrict__ enc_wt){
  __shared__ float s_cos[256];
  __shared__ float s_wi[64];
  __shared__ float s_t[64][65];
  const int t = threadIdx.x, w = t >> 6, lane = t & 63;

  if (blockIdx.x >= 1280){
    // ----- enc_w transpose: 64 K-rows/block -> bf16 tiled [K/8][64][8] -----
    const int kb = blockIdx.x - 1280;      // 256 blocks x 64 rows = 16384 K-rows
    #pragma unroll
    for (int p = 0; p < 16; ++p){
      const int row = p*4 + (t >> 6), col = t & 63;
      s_t[row][col] = enc_w[(size_t)(kb*64 + row)*64 + col];
    }
    __syncthreads();
    #pragma unroll
    for (int p = 0; p < 2; ++p){
      const int kq = p*4 + (t >> 6), c = t & 63;   // kq in [0,8): group of 8 K-rows
      short8 o;
      #pragma unroll
      for (int j = 0; j < 8; ++j) o[j] = f2b(s_t[kq*8 + j][c]);
      *(short8*)(enc_wt + ((size_t)kb*8 + kq)*512 + c*8) = o;
    }
    return;
  }

  if (blockIdx.x < 256){
    if (blockIdx.x == 0){
      #pragma unroll
      for (int i = 0; i < 8; ++i) bnsum[t + i*256] = 0.f;   // zero shadow BN accumulators
    }
    // ----- graph part: top-20 cosine + emi/emj -----
    const int i = blockIdx.x;
    if (t < 64) s_wi[t] = emb[i*64 + t];
    __syncthreads();
    float dot = 0.f, nj = 0.f, ni = 0.f;
    for (int f = 0; f < 64; ++f){
      float wj = emb[t*64 + f], wi = s_wi[f];
      dot = fmaf(wi, wj, dot); nj = fmaf(wj, wj, nj); ni = fmaf(wi, wi, ni);
    }
    s_cos[t] = dot / (sqrtf(ni) * sqrtf(nj));
    __syncthreads();
    if (t < 64){
      float v0 = s_cos[t], v1 = s_cos[t+64], v2 = s_cos[t+128], v3 = s_cos[t+192];
      int taken = 0;
      for (int r = 0; r < TK; ++r){
        float bv = (taken & 1) ? -3.f : v0; int bi = t;
        float c;
        c = (taken & 2) ? -3.f : v1; if (c > bv){ bv = c; bi = t+64;  }
        c = (taken & 4) ? -3.f : v2; if (c > bv){ bv = c; bi = t+128; }
        c = (taken & 8) ? -3.f : v3; if (c > bv){ bv = c; bi = t+192; }
        for (int m = 1; m < 64; m <<= 1){
          float ov = __shfl_xor(bv, m, 64);
          int   oi = __shfl_xor(bi, m, 64);
          if (ov > bv || (ov == bv && oi < bi)){ bv = ov; bi = oi; }
        }
        if (t == 0) topk[i*TK + r] = bi;
        if ((bi & 63) == t) taken |= 1 << (bi >> 6);
      }
    } else if (t < 128){
      int d = t - 64;
      float wv = s_wi[d];
      float p1 = wv * att_em_i[d];
      float p2 = wv * att_em_j[d];
      for (int m = 1; m < 64; m <<= 1){
        p1 += __shfl_xor(p1, m, 64);
        p2 += __shfl_xor(p2, m, 64);
      }
      if (d == 0){ emi[i] = p1; emj[i] = p2; }
    }
    return;
  }

  // ----- xl part: data @ lin_w via MFMA 16x16x32 bf16 -----
  // XCD-aligned unit mapping: block 256+j -> unit u = 4*(j&255) + (j>>8), so all
  // 4 units of batch b are written by blocks j === b (mod 8)  => one XCD per batch.
  const int m = lane & 15, quad = lane >> 4;
  short8 B[4][2];
  #pragma unroll
  for (int ct = 0; ct < 4; ++ct)
    #pragma unroll
    for (int kc = 0; kc < 2; ++kc)
      #pragma unroll
      for (int j = 0; j < 8; ++j)
        B[ct][kc][j] = f2b(lin_w[(kc*32 + quad*8 + j)*64 + ct*16 + m]);

  const int jb = blockIdx.x - 256;
  const int u  = 4*(jb & 255) + (jb >> 8);
  const int rw = u*64 + w*16;
  short8 A0, A1;
  {
    const float4* ap0 = (const float4*)(data + (size_t)(rw + m)*64 + quad*8);
    float4 q0 = ap0[0], q1 = ap0[1];
    A0[0]=f2b(q0.x); A0[1]=f2b(q0.y); A0[2]=f2b(q0.z); A0[3]=f2b(q0.w);
    A0[4]=f2b(q1.x); A0[5]=f2b(q1.y); A0[6]=f2b(q1.z); A0[7]=f2b(q1.w);
    const float4* ap1 = (const float4*)(data + (size_t)(rw + m)*64 + 32 + quad*8);
    float4 q2 = ap1[0], q3 = ap1[1];
    A1[0]=f2b(q2.x); A1[1]=f2b(q2.y); A1[2]=f2b(q2.z); A1[3]=f2b(q2.w);
    A1[4]=f2b(q3.x); A1[5]=f2b(q3.y); A1[6]=f2b(q3.z); A1[7]=f2b(q3.w);
  }
  floatx4 acc[4];
  #pragma unroll
  for (int ct = 0; ct < 4; ++ct){
    floatx4 z = {0.f, 0.f, 0.f, 0.f};
    acc[ct] = __builtin_amdgcn_mfma_f32_16x16x32_bf16(A0, B[ct][0], z, 0, 0, 0);
    acc[ct] = __builtin_amdgcn_mfma_f32_16x16x32_bf16(A1, B[ct][1], acc[ct], 0, 0, 0);
  }
  float p1[4] = {0.f,0.f,0.f,0.f}, p2[4] = {0.f,0.f,0.f,0.f};
  #pragma unroll
  for (int ct = 0; ct < 4; ++ct){
    const float wi = att_i[ct*16 + m], wj = att_j[ct*16 + m];
    #pragma unroll
    for (int reg = 0; reg < 4; ++reg){
      float v = acc[ct][reg];
      const int row = rw + quad*4 + reg;
      xl[(size_t)row*64 + ct*16 + m] = __float2bfloat16(v);
      p1[reg] = fmaf(v, wi, p1[reg]);
      p2[reg] = fmaf(v, wj, p2[reg]);
    }
  }
  #pragma unroll
  for (int reg = 0; reg < 4; ++reg){
    #pragma unroll
    for (int s = 1; s < 16; s <<= 1){
      p1[reg] += __shfl_xor(p1[reg], s, 16);
      p2[reg] += __shfl_xor(p2[reg], s, 16);
    }
    if (m == 0){
      const int r = rw + quad*4 + reg;
      aip[r] = p1[reg];                      // emi/emj added in k_attn_agg
      ajp[r] = p2[reg];
    }
  }
}

// ---------------- K2 v4: XCD-aligned consumer. 1024 blocks; block B -> batch b=B&255,
// quarter q=B>>8 (64 nodes). XCD(B)=B%8=b%8 == XCD of batch-b xl writers. ----------------
__global__ void __launch_bounds__(256) k_attn_agg(const int* __restrict__ topk,
                         const __hip_bfloat16* __restrict__ xl,
                         fpc aip, fpc ajp, fpc emi_g, fpc emj_g, fpc gnn_bias,
                         __hip_bfloat16* __restrict__ agg, float* __restrict__ bnsum,
                         int* __restrict__ ctr){
  __shared__ int    s_topk[64*TK];          // 5 KB
  __shared__ float  s_alpha[64][21];        // 5.25 KB
  __shared__ float  s_ai[64];               // aip[v] + emi[i]
  __shared__ float  s_aj[256];              // ajp[b*256+k] + emj[k]
  __shared__ float4 s_ps[16][16], s_pq[16][16];   // 8 KB
  const int t = threadIdx.x, w = t >> 6, lane = t & 63;
  const int B = blockIdx.x;
  const int b = B & 255, q = B >> 8, i0 = q*64;

  // ----- staging (coalesced, tiny; all from same-XCD L2) -----
  for (int x = t; x < 64*TK; x += 256) s_topk[x] = topk[i0*TK + x];
  s_aj[t] = ajp[b*256 + t] + emj_g[t];
  if (t < 64) s_ai[t] = aip[(size_t)b*256 + i0 + t] + emi_g[i0 + t];
  __syncthreads();

  // ----- phase 1: dual-half softmax, 16 nodes/wave, alpha -> LDS -----
  const int k32 = lane & 31, half = lane >> 5;
  #pragma unroll
  for (int j = 0; j < 8; ++j){
    const int nloc = w*16 + j*2 + half;
    const int i = i0 + nloc;
    float lg = -1e30f;
    if (k32 < 21){
      int sl = (k32 < 20) ? s_topk[nloc*TK + k32] : i;
      if (k32 == 20 || sl != i){            // remove_self_loops, keep appended loop
        float l = s_ai[nloc] + s_aj[sl];
        lg = (l >= 0.f) ? l : 0.2f*l;       // leaky_relu(0.2)
      }
    }
    float m = lg;
    for (int s = 1; s < 32; s <<= 1) m = fmaxf(m, __shfl_xor(m, s, 32));
    float e = (lg > -1e29f) ? __expf(lg - m) : 0.f;
    float den = e;
    for (int s = 1; s < 32; s <<= 1) den += __shfl_xor(den, s, 32);
    if (k32 < 21) s_alpha[nloc][k32] = e / den;   // alpha==0 for masked self-dup edges
  }
  __syncthreads();

  // ----- phase 2: aggregation, 4 nodes in parallel per wave (16 lanes/node) -----
  const int g = lane >> 4, m4 = lane & 15;  // group=node slot, m4=dim quad
  const float4 bias4 = *(const float4*)(gnn_bias + m4*4);
  const unsigned short* xb = (const unsigned short*)(xl + (size_t)b*16384);
  float4 ps = {0.f,0.f,0.f,0.f}, pq = {0.f,0.f,0.f,0.f};
  #pragma unroll
  for (int jj = 0; jj < 4; ++jj){
    const int n = w*16 + jj*4 + g;
    float4 acc = bias4;
    #pragma unroll
    for (int k = 0; k < 21; ++k){
      const int r = (k < 20) ? s_topk[n*TK + k] : (i0 + n);  // uniform per group
      const float a = s_alpha[n][k];                          // uniform per group
      ushort4 u = *(const ushort4*)(xb + r*64 + m4*4);        // 8B of gathered row
      acc.x = fmaf(a, b2fu(u.x), acc.x);
      acc.y = fmaf(a, b2fu(u.y), acc.y);
      acc.z = fmaf(a, b2fu(u.z), acc.z);
      acc.w = fmaf(a, b2fu(u.w), acc.w);
    }
    const size_t v = (size_t)b*256 + i0 + n;
    ushort4 o;
    o.x = (unsigned short)f2b(acc.x); o.y = (unsigned short)f2b(acc.y);
    o.z = (unsigned short)f2b(acc.z); o.w = (unsigned short)f2b(acc.w);
    *(ushort4*)((unsigned short*)agg + v*64 + m4*4) = o;
    ps.x += acc.x; ps.y += acc.y; ps.z += acc.z; ps.w += acc.w;
    pq.x = fmaf(acc.x, acc.x, pq.x); pq.y = fmaf(acc.y, acc.y, pq.y);
    pq.z = fmaf(acc.z, acc.z, pq.z); pq.w = fmaf(acc.w, acc.w, pq.w);
  }
  s_ps[w*4 + g][m4] = ps; s_pq[w*4 + g][m4] = pq;
  __syncthreads();
  if (t < 64){
    const int mm = t >> 2, c = t & 3;
    float S = 0.f, Q = 0.f;
    #pragma unroll
    for (int r = 0; r < 16; ++r){
      S += ((const float*)&s_ps[r][mm])[c];
      Q += ((const float*)&s_pq[r][mm])[c];
    }
    const int cp = (B & 7)*64;
    atomicAdd(&bnsum[cp + t], S);
    atomicAdd(&bnsum[512 + cp + t], Q);
  }
  LAG_TAIL(ctr);
}

// ---------------- K3: enc MFMA w/ pre-transposed B (0..255) | bn2 stats (256..2303) ----------------
__global__ void __launch_bounds__(256) k_encst(const __hip_bfloat16* __restrict__ agg,
                         const unsigned short* __restrict__ enc_wt,
                         fpc emb, fpc g1, fpc be1,
                         float* __restrict__ bnsum, float* __restrict__ part){
  const int t = threadIdx.x;
  __shared__ float s_sc[64], s_sh[64];

  // bn1 scale/shift once per block (64 threads, 16 loads each) -- bit-identical math
  if (t < 64){
    float S = 0.f, Q = 0.f;
    #pragma unroll
    for (int cp = 0; cp < 8; ++cp){ S += bnsum[cp*64 + t]; Q += bnsum[512 + cp*64 + t]; }
    float mean = S * (1.f/BN);
    float var  = Q * (1.f/BN) - mean*mean;
    float sc = g1[t] * rsqrtf(var + 1e-5f);
    s_sc[t] = sc;
    s_sh[t] = be1[t] - mean*sc;
  }
  __syncthreads();

  if (blockIdx.x < 256){
    // ===== enc path: kt in [0,128), bt in [0,2) =====
    const int w = t >> 6, lane = t & 63;
    const int m = lane & 15, quad = lane >> 4;
    const int kt = blockIdx.x & 127, bt = blockIdx.x >> 7, kbase = kt*128;
    float scA[8], shA[8], scB[8], shB[8];
    #pragma unroll
    for (int j = 0; j < 8; ++j){
      scA[j] = s_sc[quad*8 + j];      shA[j] = s_sh[quad*8 + j];
      scB[j] = s_sc[32 + quad*8 + j]; shB[j] = s_sh[32 + quad*8 + j];
    }
    floatx4 acc[2][4];
    #pragma unroll
    for (int i = 0; i < 2; ++i)
      #pragma unroll
      for (int ct = 0; ct < 4; ++ct)
        acc[i][ct] = (floatx4){0.f, 0.f, 0.f, 0.f};

    #pragma unroll
    for (int kc = 0; kc < 4; ++kc){
      const int kof = kbase + kc*32 + quad*8;
      const bool odd = (kc & 1);
      const unsigned short* bp = enc_wt + (size_t)(kof >> 3)*512 + m*8;
      short8 Bf[4];
      #pragma unroll
      for (int ct = 0; ct < 4; ++ct)
        Bf[ct] = *(const short8*)(bp + ct*128);   // fully coalesced 16B/lane
      #pragma unroll
      for (int i = 0; i < 2; ++i){
        const int row = bt*128 + (w*2 + i)*16 + m;
        uint4 uu = *(const uint4*)((const unsigned short*)agg + (size_t)row*16384 + kof);
        unsigned short h[8] = {
          (unsigned short)(uu.x & 0xffff), (unsigned short)(uu.x >> 16),
          (unsigned short)(uu.y & 0xffff), (unsigned short)(uu.y >> 16),
          (unsigned short)(uu.z & 0xffff), (unsigned short)(uu.z >> 16),
          (unsigned short)(uu.w & 0xffff), (unsigned short)(uu.w >> 16) };
        short8 Af;
        if (!odd){
          #pragma unroll
          for (int j = 0; j < 8; ++j) Af[j] = f2b(fmaxf(fmaf(b2fu(h[j]), scA[j], shA[j]), 0.f));
        } else {
          #pragma unroll
          for (int j = 0; j < 8; ++j) Af[j] = f2b(fmaxf(fmaf(b2fu(h[j]), scB[j], shB[j]), 0.f));
        }
        #pragma unroll
        for (int ct = 0; ct < 4; ++ct)
          acc[i][ct] = __builtin_amdgcn_mfma_f32_16x16x32_bf16(Af, Bf[ct], acc[i][ct], 0, 0, 0);
      }
    }
    #pragma unroll
    for (int i = 0; i < 2; ++i)
      #pragma unroll
      for (int ct = 0; ct < 4; ++ct)
        #pragma unroll
        for (int reg = 0; reg < 4; ++reg){
          const int row = bt*128 + (w*2 + i)*16 + quad*4 + reg;
          part[(size_t)row*8192 + kt*64 + ct*16 + m] = acc[i][ct][reg];  // [row][kt][dim]
        }
    return;
  }

  // ===== stats path: bn2 stats over bf16 agg (2048 blocks x 32 rows) =====
  const int sb = blockIdx.x - 256;
  const int qc = t & 15, rs = t >> 4;
  float4 sc, sh;
  sc = make_float4(s_sc[qc*4], s_sc[qc*4+1], s_sc[qc*4+2], s_sc[qc*4+3]);
  sh = make_float4(s_sh[qc*4], s_sh[qc*4+1], s_sh[qc*4+2], s_sh[qc*4+3]);
  const float4* emb4 = (const float4*)emb;
  float4 ys = make_float4(0,0,0,0), yq = make_float4(0,0,0,0);
  const int rbase = sb*32;
  #pragma unroll
  for (int jj = 0; jj < 2; ++jj){
    const int r = rbase + jj*16 + rs;
    ushort4 u = *(const ushort4*)((const unsigned short*)agg + (size_t)r*64 + qc*4);
    float4 e = emb4[(r & 255)*16 + qc];
    float4 y;
    y.x = fmaxf(fmaf(b2fu(u.x), sc.x, sh.x), 0.f) * e.x;
    y.y = fmaxf(fmaf(b2fu(u.y), sc.y, sh.y), 0.f) * e.y;
    y.z = fmaxf(fmaf(b2fu(u.z), sc.z, sh.z), 0.f) * e.z;
    y.w = fmaxf(fmaf(b2fu(u.w), sc.w, sh.w), 0.f) * e.w;
    ys.x += y.x; ys.y += y.y; ys.z += y.z; ys.w += y.w;
    yq.x = fmaf(y.x, y.x, yq.x); yq.y = fmaf(y.y, y.y, yq.y);
    yq.z = fmaf(y.z, y.z, yq.z); yq.w = fmaf(y.w, y.w, yq.w);
  }
  __shared__ float4 s_s[16][16], s_q[16][16];
  s_s[rs][qc] = ys; s_q[rs][qc] = yq;
  __syncthreads();
  if (t < 64){
    const int qq = t >> 2, comp = t & 3;
    float S = 0.f, Q = 0.f;
    #pragma unroll
    for (int rr = 0; rr < 16; ++rr){
      S += ((const float*)&s_s[rr][qq])[comp];
      Q += ((const float*)&s_q[rr][qq])[comp];
    }
    const int cp = (sb & 7)*64;
    atomicAdd(&bnsum[1024 + cp + t], S);
    atomicAdd(&bnsum[1536 + cp + t], Q);
  }
}

// ---------------- K4: redarr (0..255) | score (256..2303), bn params staged in LDS ----------------
__global__ void __launch_bounds__(256) k_fin(const float* __restrict__ part,
                      const __hip_bfloat16* __restrict__ agg, fpc emb,
                      fpc g1, fpc be1, fpc g2, fpc be2,
                      const float* __restrict__ bnsum,
                      fpc enc_b, fpc arr_w, fpc arr_b, fpc out_w, fpc out_b,
                      float* __restrict__ out){
  const int t = threadIdx.x;

  if (blockIdx.x < 256){
    // ===== redarr path: reduce split-K partials (contiguous [row][kt][dim]) + arrangement =====
    __shared__ float4 s_enc4[16][16];
    const int b = blockIdx.x;
    const int d4 = t & 15, kg = t >> 4;     // dim-quad, k-group (16 groups x 8 kt)
    float4 s = {0.f,0.f,0.f,0.f};
    #pragma unroll
    for (int j = 0; j < 8; ++j){
      float4 v = *(const float4*)(part + (size_t)b*8192 + (kg + 16*j)*64 + d4*4);
      s.x += v.x; s.y += v.y; s.z += v.z; s.w += v.w;
    }
    s_enc4[kg][d4] = s;
    __syncthreads();
    if (t < 64){
      const int mm = t >> 2, c = t & 3;
      float e = enc_b[t];
      #pragma unroll
      for (int r = 0; r < 16; ++r) e += ((const float*)&s_enc4[r][mm])[c];
      float o[7];
      #pragma unroll
      for (int j = 0; j < 7; ++j) o[j] = e * arr_w[t*7 + j];
      #pragma unroll
      for (int j = 0; j < 7; ++j)
        #pragma unroll
        for (int m = 1; m < 64; m <<= 1) o[j] += __shfl_xor(o[j], m, 64);
      if (t == 0){
        #pragma unroll
        for (int j = 0; j < 7; ++j) out[65536 + b*7 + j] = o[j] + arr_b[j];
      }
    }
    return;
  }

  // ===== score path: bn1/bn2 scale+shift computed once per block into LDS =====
  __shared__ float z1s[64], z1h[64], z2s[64], z2h[64], zow[64];
  if (t < 64){
    float S1 = 0.f, Q1 = 0.f, S2 = 0.f, Q2 = 0.f;
    #pragma unroll
    for (int cp = 0; cp < 8; ++cp){
      S1 += bnsum[cp*64 + t];        Q1 += bnsum[512 + cp*64 + t];
      S2 += bnsum[1024 + cp*64 + t]; Q2 += bnsum[1536 + cp*64 + t];
    }
    float m1 = S1 * (1.f/BN), v1 = Q1 * (1.f/BN) - m1*m1;
    float a1 = g1[t] * rsqrtf(v1 + 1e-5f);
    z1s[t] = a1; z1h[t] = be1[t] - m1*a1;
    float m2 = S2 * (1.f/BN), v2 = Q2 * (1.f/BN) - m2*m2;
    float a2 = g2[t] * rsqrtf(v2 + 1e-5f);
    z2s[t] = a2; z2h[t] = be2[t] - m2*a2;
    zow[t] = out_w[t];
  }
  __syncthreads();

  const int w = t >> 6, lane = t & 63;
  const int qc = lane & 15, rq = lane >> 4;
  float sc1[4], sh1[4], sc2[4], sh2[4], ow[4];
  #pragma unroll
  for (int k = 0; k < 4; ++k){
    const int d = qc*4 + k;
    sc1[k] = z1s[d]; sh1[k] = z1h[d];
    sc2[k] = z2s[d]; sh2[k] = z2h[d];
    ow[k]  = zow[d];
  }
  const float ob = out_b[0];
  const float4* emb4 = (const float4*)emb;
  const int base = (blockIdx.x - 256)*32 + w*8;
  #pragma unroll
  for (int it = 0; it < 2; ++it){
    const int r = base + it*4 + rq;
    ushort4 u = *(const ushort4*)((const unsigned short*)agg + (size_t)r*64 + qc*4);
    float4 e4 = emb4[(r & 255)*16 + qc];
    float p = 0.f, g, y, yh;
    g = fmaxf(fmaf(b2fu(u.x), sc1[0], sh1[0]), 0.f); y = g*e4.x;
    yh = fmaxf(fmaf(y, sc2[0], sh2[0]), 0.f); p = fmaf(yh, ow[0], p);
    g = fmaxf(fmaf(b2fu(u.y), sc1[1], sh1[1]), 0.f); y = g*e4.y;
    yh = fmaxf(fmaf(y, sc2[1], sh2[1]), 0.f); p = fmaf(yh, ow[1], p);
    g = fmaxf(fmaf(b2fu(u.z), sc1[2], sh1[2]), 0.f); y = g*e4.z;
    yh = fmaxf(fmaf(y, sc2[2], sh2[2]), 0.f); p = fmaf(yh, ow[2], p);
    g = fmaxf(fmaf(b2fu(u.w), sc1[3], sh1[3]), 0.f); y = g*e4.w;
    yh = fmaxf(fmaf(y, sc2[3], sh2[3]), 0.f); p = fmaf(yh, ow[3], p);
    #pragma unroll
    for (int mm = 1; mm < 16; mm <<= 1) p += __shfl_xor(p, mm, 16);
    if (qc == 0) out[r] = p + ob;
  }
}

extern "C" void kernel_launch(void* const* d_in, const int* in_sizes, int n_in,
                              void* d_out, int out_size, void* d_ws, size_t ws_size,
                              hipStream_t stream) {
  fpc data     = (fpc)d_in[0];
  fpc emb      = (fpc)d_in[1];
  fpc lin_w    = (fpc)d_in[2];
  fpc att_i    = (fpc)d_in[3];
  fpc att_j    = (fpc)d_in[4];
  fpc att_em_i = (fpc)d_in[5];
  fpc att_em_j = (fpc)d_in[6];
  fpc gnn_bias = (fpc)d_in[7];
  fpc g1       = (fpc)d_in[8];
  fpc be1      = (fpc)d_in[9];
  fpc g2       = (fpc)d_in[10];
  fpc be2      = (fpc)d_in[11];
  fpc enc_w    = (fpc)d_in[12];
  fpc enc_b    = (fpc)d_in[13];
  fpc arr_w    = (fpc)d_in[14];
  fpc arr_b    = (fpc)d_in[15];
  fpc out_w    = (fpc)d_in[16];
  fpc out_b    = (fpc)d_in[17];

  float* fw = (float*)d_ws;
  int*   topk    = (int*)d_ws;            // [0, 5120)
  float* emi     = fw + 5120;             // 256
  float* emj     = fw + 5376;             // 256
  float* bnsum   = fw + 5632;             // 2048 shadow BN accumulators (zeroed by k_gx block 0)
  float* aip     = fw + 7680;             // 65536
  float* ajp     = fw + 73216;            // 65536
  __hip_bfloat16* agg = (__hip_bfloat16*)(fw + 138752);  // 65536*64 bf16 = 8.39 MB
  __hip_bfloat16* xl  = (__hip_bfloat16*)(fw + 2235904); // 65536*64 bf16 = 8.39 MB
  float* part    = (float*)xl;            // 256*128*64 f32 [row][kt][dim] = 8.39 MB, aliases dead xl
  int*   ctr     = (int*)(fw + 5000000);  // lag counters, past live data
  unsigned short* enc_wt = (unsigned short*)(fw + 5242880); // 16384x64 bf16 tiled = 2 MB
  float* out     = (float*)d_out;

  hipMemsetAsync(ctr, 0, 4*sizeof(int), stream);

  k_gx       <<<1536,  256, 0, stream>>>(data, emb, lin_w, att_i, att_j, att_em_i, att_em_j,
                                         enc_w, topk, emi, emj, xl, aip, ajp, bnsum, enc_wt);
  k_attn_agg <<<1024,  256, 0, stream>>>(topk, xl, aip, ajp, emi, emj, gnn_bias, agg, bnsum, ctr+1);
  k_encst    <<<2304,  256, 0, stream>>>(agg, enc_wt, emb, g1, be1, bnsum, part);
  k_fin      <<<2304,  256, 0, stream>>>(part, agg, emb, g1, be1, g2, be2, bnsum,
                                         enc_b, arr_w, arr_b, out_w, out_b, out);
}

// Round 8
// 148.426 us; speedup vs baseline: 2.8401x; 1.4321x over previous
//
#include <hip/hip_runtime.h>
#include <hip/hip_bf16.h>

#define TK 20
#define BN 65536

typedef const float* fpc;
typedef __attribute__((ext_vector_type(8))) short short8;
typedef __attribute__((ext_vector_type(4))) float floatx4;

// f32 -> bf16 bits, round-to-nearest-even
__device__ __forceinline__ short f2b(float f){
  unsigned u = __float_as_uint(f);
  return (short)((u + 0x7fffu + ((u >> 16) & 1u)) >> 16);
}
__device__ __forceinline__ float b2fu(unsigned short u){
  return __uint_as_float(((unsigned)u) << 16);
}

// ---------------- K1: graph (0..255, block 0 zeroes bnsum) | xl MFMA (256..1279, XCD-aligned) | enc_w transpose (1280..1535) ----------------
__global__ void __launch_bounds__(256) k_gx(fpc data, fpc emb, fpc lin_w, fpc att_i, fpc att_j,
        fpc att_em_i, fpc att_em_j, fpc enc_w,
        int* __restrict__ topk, float* __restrict__ emi, float* __restrict__ emj,
        __hip_bfloat16* __restrict__ xl, float* __restrict__ aip, float* __restrict__ ajp,
        float* __restrict__ bnsum, unsigned short* __restrict__ enc_wt){
  __shared__ float s_cos[256];
  __shared__ float s_wi[64];
  __shared__ float s_t[64][65];
  const int t = threadIdx.x, w = t >> 6, lane = t & 63;

  if (blockIdx.x >= 1280){
    // ----- enc_w transpose: 64 K-rows/block -> bf16 tiled [K/8][64][8] -----
    const int kb = blockIdx.x - 1280;      // 256 blocks x 64 rows = 16384 K-rows
    #pragma unroll
    for (int p = 0; p < 16; ++p){
      const int row = p*4 + (t >> 6), col = t & 63;
      s_t[row][col] = enc_w[(size_t)(kb*64 + row)*64 + col];
    }
    __syncthreads();
    #pragma unroll
    for (int p = 0; p < 2; ++p){
      const int kq = p*4 + (t >> 6), c = t & 63;   // kq in [0,8): group of 8 K-rows
      short8 o;
      #pragma unroll
      for (int j = 0; j < 8; ++j) o[j] = f2b(s_t[kq*8 + j][c]);
      *(short8*)(enc_wt + ((size_t)kb*8 + kq)*512 + c*8) = o;
    }
    return;
  }

  if (blockIdx.x < 256){
    if (blockIdx.x == 0){
      #pragma unroll
      for (int i = 0; i < 8; ++i) bnsum[t + i*256] = 0.f;   // zero shadow BN accumulators
    }
    // ----- graph part: top-20 cosine + emi/emj -----
    const int i = blockIdx.x;
    if (t < 64) s_wi[t] = emb[i*64 + t];
    __syncthreads();
    // float4-vectorized cosine, fmaf order preserved (f ascending) -> bit-identical
    float dot = 0.f, nj = 0.f, ni = 0.f;
    const float4* er = (const float4*)(emb + (size_t)t*64);
    #pragma unroll
    for (int fq = 0; fq < 16; ++fq){
      float4 a4 = er[fq];
      float4 w4 = *(const float4*)&s_wi[fq*4];
      dot = fmaf(w4.x, a4.x, dot); nj = fmaf(a4.x, a4.x, nj); ni = fmaf(w4.x, w4.x, ni);
      dot = fmaf(w4.y, a4.y, dot); nj = fmaf(a4.y, a4.y, nj); ni = fmaf(w4.y, w4.y, ni);
      dot = fmaf(w4.z, a4.z, dot); nj = fmaf(a4.z, a4.z, nj); ni = fmaf(w4.z, w4.z, ni);
      dot = fmaf(w4.w, a4.w, dot); nj = fmaf(a4.w, a4.w, nj); ni = fmaf(w4.w, w4.w, ni);
    }
    s_cos[t] = dot / (sqrtf(ni) * sqrtf(nj));
    __syncthreads();
    if (t < 64){
      float v0 = s_cos[t], v1 = s_cos[t+64], v2 = s_cos[t+128], v3 = s_cos[t+192];
      int taken = 0;
      for (int r = 0; r < TK; ++r){
        float bv = (taken & 1) ? -3.f : v0; int bi = t;
        float c;
        c = (taken & 2) ? -3.f : v1; if (c > bv){ bv = c; bi = t+64;  }
        c = (taken & 4) ? -3.f : v2; if (c > bv){ bv = c; bi = t+128; }
        c = (taken & 8) ? -3.f : v3; if (c > bv){ bv = c; bi = t+192; }
        for (int m = 1; m < 64; m <<= 1){
          float ov = __shfl_xor(bv, m, 64);
          int   oi = __shfl_xor(bi, m, 64);
          if (ov > bv || (ov == bv && oi < bi)){ bv = ov; bi = oi; }
        }
        if (t == 0) topk[i*TK + r] = bi;
        if ((bi & 63) == t) taken |= 1 << (bi >> 6);
      }
    } else if (t < 128){
      int d = t - 64;
      float wv = s_wi[d];
      float p1 = wv * att_em_i[d];
      float p2 = wv * att_em_j[d];
      for (int m = 1; m < 64; m <<= 1){
        p1 += __shfl_xor(p1, m, 64);
        p2 += __shfl_xor(p2, m, 64);
      }
      if (d == 0){ emi[i] = p1; emj[i] = p2; }
    }
    return;
  }

  // ----- xl part: data @ lin_w via MFMA 16x16x32 bf16 -----
  // XCD-aligned unit mapping: block 256+j -> unit u = 4*(j&255) + (j>>8), so all
  // 4 units of batch b are written by blocks j === b (mod 8)  => one XCD per batch.
  const int m = lane & 15, quad = lane >> 4;
  short8 B[4][2];
  #pragma unroll
  for (int ct = 0; ct < 4; ++ct)
    #pragma unroll
    for (int kc = 0; kc < 2; ++kc)
      #pragma unroll
      for (int j = 0; j < 8; ++j)
        B[ct][kc][j] = f2b(lin_w[(kc*32 + quad*8 + j)*64 + ct*16 + m]);

  const int jb = blockIdx.x - 256;
  const int u  = 4*(jb & 255) + (jb >> 8);
  const int rw = u*64 + w*16;
  short8 A0, A1;
  {
    const float4* ap0 = (const float4*)(data + (size_t)(rw + m)*64 + quad*8);
    float4 q0 = ap0[0], q1 = ap0[1];
    A0[0]=f2b(q0.x); A0[1]=f2b(q0.y); A0[2]=f2b(q0.z); A0[3]=f2b(q0.w);
    A0[4]=f2b(q1.x); A0[5]=f2b(q1.y); A0[6]=f2b(q1.z); A0[7]=f2b(q1.w);
    const float4* ap1 = (const float4*)(data + (size_t)(rw + m)*64 + 32 + quad*8);
    float4 q2 = ap1[0], q3 = ap1[1];
    A1[0]=f2b(q2.x); A1[1]=f2b(q2.y); A1[2]=f2b(q2.z); A1[3]=f2b(q2.w);
    A1[4]=f2b(q3.x); A1[5]=f2b(q3.y); A1[6]=f2b(q3.z); A1[7]=f2b(q3.w);
  }
  floatx4 acc[4];
  #pragma unroll
  for (int ct = 0; ct < 4; ++ct){
    floatx4 z = {0.f, 0.f, 0.f, 0.f};
    acc[ct] = __builtin_amdgcn_mfma_f32_16x16x32_bf16(A0, B[ct][0], z, 0, 0, 0);
    acc[ct] = __builtin_amdgcn_mfma_f32_16x16x32_bf16(A1, B[ct][1], acc[ct], 0, 0, 0);
  }
  float p1[4] = {0.f,0.f,0.f,0.f}, p2[4] = {0.f,0.f,0.f,0.f};
  #pragma unroll
  for (int ct = 0; ct < 4; ++ct){
    const float wi = att_i[ct*16 + m], wj = att_j[ct*16 + m];
    #pragma unroll
    for (int reg = 0; reg < 4; ++reg){
      float v = acc[ct][reg];
      const int row = rw + quad*4 + reg;
      xl[(size_t)row*64 + ct*16 + m] = __float2bfloat16(v);
      p1[reg] = fmaf(v, wi, p1[reg]);
      p2[reg] = fmaf(v, wj, p2[reg]);
    }
  }
  #pragma unroll
  for (int reg = 0; reg < 4; ++reg){
    #pragma unroll
    for (int s = 1; s < 16; s <<= 1){
      p1[reg] += __shfl_xor(p1[reg], s, 16);
      p2[reg] += __shfl_xor(p2[reg], s, 16);
    }
    if (m == 0){
      const int r = rw + quad*4 + reg;
      aip[r] = p1[reg];                      // emi/emj added in k_attn_agg
      ajp[r] = p2[reg];
    }
  }
}

// ---------------- K2 v5: 2048 XCD-aligned blocks (32 nodes). b = B&255 => XCD(B)=b%8
// matches batch-b xl writers; 8 blocks/CU = 100% occupancy. ----------------
__global__ void __launch_bounds__(256) k_attn_agg(const int* __restrict__ topk,
                         const __hip_bfloat16* __restrict__ xl,
                         fpc aip, fpc ajp, fpc emi_g, fpc emj_g, fpc gnn_bias,
                         __hip_bfloat16* __restrict__ agg, float* __restrict__ bnsum){
  __shared__ int    s_topk[32*TK];          // 2.5 KB
  __shared__ float  s_alpha[32][21];        // 2.7 KB
  __shared__ float  s_ai[32];               // aip[v] + emi[i]
  __shared__ float  s_aj[256];              // ajp[b*256+k] + emj[k]
  __shared__ float4 s_ps[16][16], s_pq[16][16];   // 8 KB
  const int t = threadIdx.x, w = t >> 6, lane = t & 63;
  const int B = blockIdx.x;
  const int b = B & 255, q = B >> 8, i0 = q*32;   // XCD-aligned with xl producer

  // ----- staging (coalesced, tiny; same-XCD L2) -----
  for (int x = t; x < 32*TK; x += 256) s_topk[x] = topk[i0*TK + x];
  s_aj[t] = ajp[b*256 + t] + emj_g[t];
  if (t < 32) s_ai[t] = aip[(size_t)b*256 + i0 + t] + emi_g[i0 + t];
  __syncthreads();

  // ----- phase 1: dual-half softmax, 8 nodes/wave, alpha -> LDS -----
  const int k32 = lane & 31, half = lane >> 5;
  #pragma unroll
  for (int j = 0; j < 4; ++j){
    const int nloc = w*8 + j*2 + half;
    const int i = i0 + nloc;
    float lg = -1e30f;
    if (k32 < 21){
      int sl = (k32 < 20) ? s_topk[nloc*TK + k32] : i;
      if (k32 == 20 || sl != i){            // remove_self_loops, keep appended loop
        float l = s_ai[nloc] + s_aj[sl];
        lg = (l >= 0.f) ? l : 0.2f*l;       // leaky_relu(0.2)
      }
    }
    float m = lg;
    for (int s = 1; s < 32; s <<= 1) m = fmaxf(m, __shfl_xor(m, s, 32));
    float e = (lg > -1e29f) ? __expf(lg - m) : 0.f;
    float den = e;
    for (int s = 1; s < 32; s <<= 1) den += __shfl_xor(den, s, 32);
    if (k32 < 21) s_alpha[nloc][k32] = e / den;   // alpha==0 for masked self-dup edges
  }
  __syncthreads();

  // ----- phase 2: aggregation, 4 nodes in parallel per wave (16 lanes/node) -----
  const int g = lane >> 4, m4 = lane & 15;  // group=node slot, m4=dim quad
  const float4 bias4 = *(const float4*)(gnn_bias + m4*4);
  const unsigned short* xb = (const unsigned short*)(xl + (size_t)b*16384);
  float4 ps = {0.f,0.f,0.f,0.f}, pq = {0.f,0.f,0.f,0.f};
  #pragma unroll
  for (int jj = 0; jj < 2; ++jj){
    const int n = w*8 + jj*4 + g;
    float4 acc = bias4;
    #pragma unroll
    for (int k = 0; k < 21; ++k){
      const int r = (k < 20) ? s_topk[n*TK + k] : (i0 + n);  // uniform per group
      const float a = s_alpha[n][k];                          // uniform per group
      ushort4 u = *(const ushort4*)(xb + r*64 + m4*4);        // 8B of gathered row
      acc.x = fmaf(a, b2fu(u.x), acc.x);
      acc.y = fmaf(a, b2fu(u.y), acc.y);
      acc.z = fmaf(a, b2fu(u.z), acc.z);
      acc.w = fmaf(a, b2fu(u.w), acc.w);
    }
    const size_t v = (size_t)b*256 + i0 + n;
    ushort4 o;
    o.x = (unsigned short)f2b(acc.x); o.y = (unsigned short)f2b(acc.y);
    o.z = (unsigned short)f2b(acc.z); o.w = (unsigned short)f2b(acc.w);
    *(ushort4*)((unsigned short*)agg + v*64 + m4*4) = o;
    ps.x += acc.x; ps.y += acc.y; ps.z += acc.z; ps.w += acc.w;
    pq.x = fmaf(acc.x, acc.x, pq.x); pq.y = fmaf(acc.y, acc.y, pq.y);
    pq.z = fmaf(acc.z, acc.z, pq.z); pq.w = fmaf(acc.w, acc.w, pq.w);
  }
  s_ps[w*4 + g][m4] = ps; s_pq[w*4 + g][m4] = pq;
  __syncthreads();
  if (t < 64){
    const int mm = t >> 2, c = t & 3;
    float S = 0.f, Q = 0.f;
    #pragma unroll
    for (int r = 0; r < 16; ++r){
      S += ((const float*)&s_ps[r][mm])[c];
      Q += ((const float*)&s_pq[r][mm])[c];
    }
    const int cp = (B & 7)*64;
    atomicAdd(&bnsum[cp + t], S);
    atomicAdd(&bnsum[512 + cp + t], Q);
  }
}

// ---------------- K3: enc MFMA w/ pre-transposed B (0..255) | bn2 stats (256..2303) ----------------
__global__ void __launch_bounds__(256) k_encst(const __hip_bfloat16* __restrict__ agg,
                         const unsigned short* __restrict__ enc_wt,
                         fpc emb, fpc g1, fpc be1,
                         float* __restrict__ bnsum, float* __restrict__ part){
  const int t = threadIdx.x;
  __shared__ float s_sc[64], s_sh[64];

  // bn1 scale/shift once per block (64 threads, 16 loads each) -- bit-identical math
  if (t < 64){
    float S = 0.f, Q = 0.f;
    #pragma unroll
    for (int cp = 0; cp < 8; ++cp){ S += bnsum[cp*64 + t]; Q += bnsum[512 + cp*64 + t]; }
    float mean = S * (1.f/BN);
    float var  = Q * (1.f/BN) - mean*mean;
    float sc = g1[t] * rsqrtf(var + 1e-5f);
    s_sc[t] = sc;
    s_sh[t] = be1[t] - mean*sc;
  }
  __syncthreads();

  if (blockIdx.x < 256){
    // ===== enc path: kt in [0,128), bt in [0,2) =====
    const int w = t >> 6, lane = t & 63;
    const int m = lane & 15, quad = lane >> 4;
    const int kt = blockIdx.x & 127, bt = blockIdx.x >> 7, kbase = kt*128;
    float scA[8], shA[8], scB[8], shB[8];
    #pragma unroll
    for (int j = 0; j < 8; ++j){
      scA[j] = s_sc[quad*8 + j];      shA[j] = s_sh[quad*8 + j];
      scB[j] = s_sc[32 + quad*8 + j]; shB[j] = s_sh[32 + quad*8 + j];
    }
    floatx4 acc[2][4];
    #pragma unroll
    for (int i = 0; i < 2; ++i)
      #pragma unroll
      for (int ct = 0; ct < 4; ++ct)
        acc[i][ct] = (floatx4){0.f, 0.f, 0.f, 0.f};

    #pragma unroll
    for (int kc = 0; kc < 4; ++kc){
      const int kof = kbase + kc*32 + quad*8;
      const bool odd = (kc & 1);
      const unsigned short* bp = enc_wt + (size_t)(kof >> 3)*512 + m*8;
      short8 Bf[4];
      #pragma unroll
      for (int ct = 0; ct < 4; ++ct)
        Bf[ct] = *(const short8*)(bp + ct*128);   // fully coalesced 16B/lane
      #pragma unroll
      for (int i = 0; i < 2; ++i){
        const int row = bt*128 + (w*2 + i)*16 + m;
        uint4 uu = *(const uint4*)((const unsigned short*)agg + (size_t)row*16384 + kof);
        unsigned short h[8] = {
          (unsigned short)(uu.x & 0xffff), (unsigned short)(uu.x >> 16),
          (unsigned short)(uu.y & 0xffff), (unsigned short)(uu.y >> 16),
          (unsigned short)(uu.z & 0xffff), (unsigned short)(uu.z >> 16),
          (unsigned short)(uu.w & 0xffff), (unsigned short)(uu.w >> 16) };
        short8 Af;
        if (!odd){
          #pragma unroll
          for (int j = 0; j < 8; ++j) Af[j] = f2b(fmaxf(fmaf(b2fu(h[j]), scA[j], shA[j]), 0.f));
        } else {
          #pragma unroll
          for (int j = 0; j < 8; ++j) Af[j] = f2b(fmaxf(fmaf(b2fu(h[j]), scB[j], shB[j]), 0.f));
        }
        #pragma unroll
        for (int ct = 0; ct < 4; ++ct)
          acc[i][ct] = __builtin_amdgcn_mfma_f32_16x16x32_bf16(Af, Bf[ct], acc[i][ct], 0, 0, 0);
      }
    }
    #pragma unroll
    for (int i = 0; i < 2; ++i)
      #pragma unroll
      for (int ct = 0; ct < 4; ++ct)
        #pragma unroll
        for (int reg = 0; reg < 4; ++reg){
          const int row = bt*128 + (w*2 + i)*16 + quad*4 + reg;
          part[(size_t)row*8192 + kt*64 + ct*16 + m] = acc[i][ct][reg];  // [row][kt][dim]
        }
    return;
  }

  // ===== stats path: bn2 stats over bf16 agg (2048 blocks x 32 rows) =====
  const int sb = blockIdx.x - 256;
  const int qc = t & 15, rs = t >> 4;
  float4 sc, sh;
  sc = make_float4(s_sc[qc*4], s_sc[qc*4+1], s_sc[qc*4+2], s_sc[qc*4+3]);
  sh = make_float4(s_sh[qc*4], s_sh[qc*4+1], s_sh[qc*4+2], s_sh[qc*4+3]);
  const float4* emb4 = (const float4*)emb;
  float4 ys = make_float4(0,0,0,0), yq = make_float4(0,0,0,0);
  const int rbase = sb*32;
  #pragma unroll
  for (int jj = 0; jj < 2; ++jj){
    const int r = rbase + jj*16 + rs;
    ushort4 u = *(const ushort4*)((const unsigned short*)agg + (size_t)r*64 + qc*4);
    float4 e = emb4[(r & 255)*16 + qc];
    float4 y;
    y.x = fmaxf(fmaf(b2fu(u.x), sc.x, sh.x), 0.f) * e.x;
    y.y = fmaxf(fmaf(b2fu(u.y), sc.y, sh.y), 0.f) * e.y;
    y.z = fmaxf(fmaf(b2fu(u.z), sc.z, sh.z), 0.f) * e.z;
    y.w = fmaxf(fmaf(b2fu(u.w), sc.w, sh.w), 0.f) * e.w;
    ys.x += y.x; ys.y += y.y; ys.z += y.z; ys.w += y.w;
    yq.x = fmaf(y.x, y.x, yq.x); yq.y = fmaf(y.y, y.y, yq.y);
    yq.z = fmaf(y.z, y.z, yq.z); yq.w = fmaf(y.w, y.w, yq.w);
  }
  __shared__ float4 s_s[16][16], s_q[16][16];
  s_s[rs][qc] = ys; s_q[rs][qc] = yq;
  __syncthreads();
  if (t < 64){
    const int qq = t >> 2, comp = t & 3;
    float S = 0.f, Q = 0.f;
    #pragma unroll
    for (int rr = 0; rr < 16; ++rr){
      S += ((const float*)&s_s[rr][qq])[comp];
      Q += ((const float*)&s_q[rr][qq])[comp];
    }
    const int cp = (sb & 7)*64;
    atomicAdd(&bnsum[1024 + cp + t], S);
    atomicAdd(&bnsum[1536 + cp + t], Q);
  }
}

// ---------------- K4: redarr (0..255) | score (256..2303), bn params staged in LDS ----------------
__global__ void __launch_bounds__(256) k_fin(const float* __restrict__ part,
                      const __hip_bfloat16* __restrict__ agg, fpc emb,
                      fpc g1, fpc be1, fpc g2, fpc be2,
                      const float* __restrict__ bnsum,
                      fpc enc_b, fpc arr_w, fpc arr_b, fpc out_w, fpc out_b,
                      float* __restrict__ out){
  const int t = threadIdx.x;

  if (blockIdx.x < 256){
    // ===== redarr path: reduce split-K partials (contiguous [row][kt][dim]) + arrangement =====
    __shared__ float4 s_enc4[16][16];
    const int b = blockIdx.x;
    const int d4 = t & 15, kg = t >> 4;     // dim-quad, k-group (16 groups x 8 kt)
    float4 s = {0.f,0.f,0.f,0.f};
    #pragma unroll
    for (int j = 0; j < 8; ++j){
      float4 v = *(const float4*)(part + (size_t)b*8192 + (kg + 16*j)*64 + d4*4);
      s.x += v.x; s.y += v.y; s.z += v.z; s.w += v.w;
    }
    s_enc4[kg][d4] = s;
    __syncthreads();
    if (t < 64){
      const int mm = t >> 2, c = t & 3;
      float e = enc_b[t];
      #pragma unroll
      for (int r = 0; r < 16; ++r) e += ((const float*)&s_enc4[r][mm])[c];
      float o[7];
      #pragma unroll
      for (int j = 0; j < 7; ++j) o[j] = e * arr_w[t*7 + j];
      #pragma unroll
      for (int j = 0; j < 7; ++j)
        #pragma unroll
        for (int m = 1; m < 64; m <<= 1) o[j] += __shfl_xor(o[j], m, 64);
      if (t == 0){
        #pragma unroll
        for (int j = 0; j < 7; ++j) out[65536 + b*7 + j] = o[j] + arr_b[j];
      }
    }
    return;
  }

  // ===== score path: bn1/bn2 scale+shift computed once per block into LDS =====
  __shared__ float z1s[64], z1h[64], z2s[64], z2h[64], zow[64];
  if (t < 64){
    float S1 = 0.f, Q1 = 0.f, S2 = 0.f, Q2 = 0.f;
    #pragma unroll
    for (int cp = 0; cp < 8; ++cp){
      S1 += bnsum[cp*64 + t];        Q1 += bnsum[512 + cp*64 + t];
      S2 += bnsum[1024 + cp*64 + t]; Q2 += bnsum[1536 + cp*64 + t];
    }
    float m1 = S1 * (1.f/BN), v1 = Q1 * (1.f/BN) - m1*m1;
    float a1 = g1[t] * rsqrtf(v1 + 1e-5f);
    z1s[t] = a1; z1h[t] = be1[t] - m1*a1;
    float m2 = S2 * (1.f/BN), v2 = Q2 * (1.f/BN) - m2*m2;
    float a2 = g2[t] * rsqrtf(v2 + 1e-5f);
    z2s[t] = a2; z2h[t] = be2[t] - m2*a2;
    zow[t] = out_w[t];
  }
  __syncthreads();

  const int w = t >> 6, lane = t & 63;
  const int qc = lane & 15, rq = lane >> 4;
  float sc1[4], sh1[4], sc2[4], sh2[4], ow[4];
  #pragma unroll
  for (int k = 0; k < 4; ++k){
    const int d = qc*4 + k;
    sc1[k] = z1s[d]; sh1[k] = z1h[d];
    sc2[k] = z2s[d]; sh2[k] = z2h[d];
    ow[k]  = zow[d];
  }
  const float ob = out_b[0];
  const float4* emb4 = (const float4*)emb;
  const int base = (blockIdx.x - 256)*32 + w*8;
  #pragma unroll
  for (int it = 0; it < 2; ++it){
    const int r = base + it*4 + rq;
    ushort4 u = *(const ushort4*)((const unsigned short*)agg + (size_t)r*64 + qc*4);
    float4 e4 = emb4[(r & 255)*16 + qc];
    float p = 0.f, g, y, yh;
    g = fmaxf(fmaf(b2fu(u.x), sc1[0], sh1[0]), 0.f); y = g*e4.x;
    yh = fmaxf(fmaf(y, sc2[0], sh2[0]), 0.f); p = fmaf(yh, ow[0], p);
    g = fmaxf(fmaf(b2fu(u.y), sc1[1], sh1[1]), 0.f); y = g*e4.y;
    yh = fmaxf(fmaf(y, sc2[1], sh2[1]), 0.f); p = fmaf(yh, ow[1], p);
    g = fmaxf(fmaf(b2fu(u.z), sc1[2], sh1[2]), 0.f); y = g*e4.z;
    yh = fmaxf(fmaf(y, sc2[2], sh2[2]), 0.f); p = fmaf(yh, ow[2], p);
    g = fmaxf(fmaf(b2fu(u.w), sc1[3], sh1[3]), 0.f); y = g*e4.w;
    yh = fmaxf(fmaf(y, sc2[3], sh2[3]), 0.f); p = fmaf(yh, ow[3], p);
    #pragma unroll
    for (int mm = 1; mm < 16; mm <<= 1) p += __shfl_xor(p, mm, 16);
    if (qc == 0) out[r] = p + ob;
  }
}

extern "C" void kernel_launch(void* const* d_in, const int* in_sizes, int n_in,
                              void* d_out, int out_size, void* d_ws, size_t ws_size,
                              hipStream_t stream) {
  fpc data     = (fpc)d_in[0];
  fpc emb      = (fpc)d_in[1];
  fpc lin_w    = (fpc)d_in[2];
  fpc att_i    = (fpc)d_in[3];
  fpc att_j    = (fpc)d_in[4];
  fpc att_em_i = (fpc)d_in[5];
  fpc att_em_j = (fpc)d_in[6];
  fpc gnn_bias = (fpc)d_in[7];
  fpc g1       = (fpc)d_in[8];
  fpc be1      = (fpc)d_in[9];
  fpc g2       = (fpc)d_in[10];
  fpc be2      = (fpc)d_in[11];
  fpc enc_w    = (fpc)d_in[12];
  fpc enc_b    = (fpc)d_in[13];
  fpc arr_w    = (fpc)d_in[14];
  fpc arr_b    = (fpc)d_in[15];
  fpc out_w    = (fpc)d_in[16];
  fpc out_b    = (fpc)d_in[17];

  float* fw = (float*)d_ws;
  int*   topk    = (int*)d_ws;            // [0, 5120)
  float* emi     = fw + 5120;             // 256
  float* emj     = fw + 5376;             // 256
  float* bnsum   = fw + 5632;             // 2048 shadow BN accumulators (zeroed by k_gx block 0)
  float* aip     = fw + 7680;             // 65536
  float* ajp     = fw + 73216;            // 65536
  __hip_bfloat16* agg = (__hip_bfloat16*)(fw + 138752);  // 65536*64 bf16 = 8.39 MB
  __hip_bfloat16* xl  = (__hip_bfloat16*)(fw + 2235904); // 65536*64 bf16 = 8.39 MB
  float* part    = (float*)xl;            // 256*128*64 f32 [row][kt][dim] = 8.39 MB, aliases dead xl
  unsigned short* enc_wt = (unsigned short*)(fw + 5242880); // 16384x64 bf16 tiled = 2 MB
  float* out     = (float*)d_out;

  k_gx       <<<1536,  256, 0, stream>>>(data, emb, lin_w, att_i, att_j, att_em_i, att_em_j,
                                         enc_w, topk, emi, emj, xl, aip, ajp, bnsum, enc_wt);
  k_attn_agg <<<2048,  256, 0, stream>>>(topk, xl, aip, ajp, emi, emj, gnn_bias, agg, bnsum);
  k_encst    <<<2304,  256, 0, stream>>>(agg, enc_wt, emb, g1, be1, bnsum, part);
  k_fin      <<<2304,  256, 0, stream>>>(part, agg, emb, g1, be1, g2, be2, bnsum,
                                         enc_b, arr_w, arr_b, out_w, out_b, out);
}